// Round 7
// baseline (2260.236 us; speedup 1.0000x reference)
//
#include <hip/hip_runtime.h>
#include <math.h>

// ---------------- problem constants ----------------
constexpr int NB = 4;            // batch
constexpr int NC = 512;          // channels
constexpr int NH = 64, NW = 64;  // spatial
constexpr int NPOS = NH * NW;        // 4096
constexpr int NANCH = NPOS * 9;      // 36864 anchors/batch
constexpr int PRE_TOPN = 6000;
constexpr int POST_TOPN = 300;
constexpr int CAND_CAP = 40960;
constexpr int MROW = 96;             // mask row stride in u64 (94 used)

// anchors for base_size=16, ratios {0.5,1,2}, scales {8,16,32} (verified vs numpy)
__device__ __constant__ float A9c[9][4] = {
  {-84.f,-40.f,99.f,55.f},   {-176.f,-88.f,191.f,103.f}, {-360.f,-184.f,375.f,199.f},
  {-56.f,-56.f,71.f,71.f},   {-120.f,-120.f,135.f,135.f},{-248.f,-248.f,263.f,263.f},
  {-36.f,-80.f,51.f,95.f},   {-80.f,-168.f,95.f,183.f},  {-168.f,-344.f,183.f,359.f}};

// ---------------- ws layout (bytes) ----------------
constexpr size_t OFF_WT    = 0;                       // 512*512*9*4      = 9,437,184
constexpr size_t OFF_CONV  = 9437184;                 // 4*512*4096*4     = 33,554,432 (reused as IoU mask after heads)
constexpr size_t OFF_MASK  = OFF_CONV;                // 4*6000*96*8      = 18,432,000 (overlay)
constexpr size_t OFF_HEAD  = 42991616;                // 4*54*4096*4      = 3,538,944
constexpr size_t OFF_SKEY  = 46530560;                // 4*36864*4        = 589,824
constexpr size_t OFF_BOX   = 47120384;                // 4*36864*4*4      = 2,359,296
constexpr size_t OFF_HIST  = 49479680;                // 4*4096*4         = 65,536
constexpr size_t OFF_HIST2 = 49545216;                // 4*256*4          = 4,096
constexpr size_t OFF_MISC  = 49549312;                // 256
constexpr size_t OFF_CKEY  = 49549568;                // 4*40960*4        = 655,360
constexpr size_t OFF_CIDX  = 50204928;                // 4*40960*4        = 655,360
constexpr size_t OFF_SBOX  = 50860288;                // 4*6000*4*4       = 384,000
// total ≈ 51.2 MB

// ---------------- weight transpose: W[ko][c][tap] -> Wt[c][tap][ko] ----------------
__global__ __launch_bounds__(256) void wtrans_k(const float* __restrict__ Wc,
                                               float* __restrict__ Wt) {
  int i = blockIdx.x * 256 + threadIdx.x;
  if (i >= 512 * 512 * 9) return;
  int ko = i / 4608; int r = i - ko * 4608; int c = r / 9; int tap = r - c * 9;
  Wt[((size_t)c * 9 + tap) * 512 + ko] = Wc[i];
}

// ---------------- 3x3 conv + bias + relu (fp32, 4ko x 2y x 8x per thread) ----------------
// Block: 128 threads, 32 ko x 4 y x 64 x. Grid (16,16,4) = 1024 blocks = 4/CU.
// y-reuse: staged row r feeds outputs yy=0 (dy=r) and yy=1 (dy=r-1) -> 0.53 LDS B/FMA.
// Per-output accumulation order: c ascending, dy ascending, dx ascending —
// bit-identical to all previous passing kernels (selection depends on exact fp32 bits).
__global__ __launch_bounds__(128, 2) void conv3x3_relu_k(
    const float* __restrict__ in, const float* __restrict__ Wt,
    const float* __restrict__ bias, float* __restrict__ out) {
  __shared__ float Ilds[48][68];      // row = cc*6 + yy (8 c x 6 y incl halo); 66 cols used
  __shared__ float Wlds[8][9][32];    // c, tap, ko
  const int ko0 = blockIdx.x * 32;    // 16 ko-blocks
  const int ty0 = blockIdx.y * 4;     // 16 y-tiles
  const int b   = blockIdx.z;
  const int tid = threadIdx.x;
  const int tk4  = (tid & 7) * 4;          // 4 kout per thread
  const int tyy2 = ((tid >> 3) & 1) * 2;   // y-pair base (0 or 2)
  const int txx8 = (tid >> 4) * 8;         // 8 x per thread

  float acc[4][2][8] = {};
  const float* inb = in + (size_t)b * NC * NPOS;

  for (int c0 = 0; c0 < NC; c0 += 8) {
    __syncthreads();
    // stage input: col j holds gx = j-1. Main cols 0..63 (gx -1..62):
    for (int e = tid; e < 48 * 64; e += 128) {
      int r = e >> 6, xx = e & 63;
      int cc = r / 6; int yy = r - cc * 6;
      int gy = ty0 + yy - 1, gx = xx - 1;
      float v = 0.f;
      if ((unsigned)gy < 64u && (unsigned)gx < 64u)
        v = inb[(size_t)(c0 + cc) * NPOS + gy * 64 + gx];
      Ilds[r][xx] = v;
    }
    // halo cols 64,65 (gx 63,64):
    if (tid < 96) {
      int r = tid >> 1, j = tid & 1;
      int cc = r / 6; int yy = r - cc * 6;
      int gy = ty0 + yy - 1, gx = 63 + j;
      float v = 0.f;
      if ((unsigned)gy < 64u && gx < 64)
        v = inb[(size_t)(c0 + cc) * NPOS + gy * 64 + gx];
      Ilds[r][64 + j] = v;
    }
    // stage weights 8 x 9 x 32 = 2304 elems; destination linear in e
    for (int e = tid; e < 8 * 9 * 32; e += 128) {
      int ko = e & 31; int r = e >> 5; int tap = r % 9; int cc = r / 9;
      ((float*)Wlds)[e] = Wt[(size_t)(c0 + cc) * 4608 + tap * 512 + ko0 + ko];
    }
    __syncthreads();
    #pragma unroll 2
    for (int cc = 0; cc < 8; ++cc) {
      // all 9 taps' weights for this cc in registers (reused by both y-outputs)
      float4 wt[9];
      #pragma unroll
      for (int t = 0; t < 9; ++t) wt[t] = *(const float4*)&Wlds[cc][t][tk4];
      const int rbase = cc * 6 + tyy2;
      #pragma unroll
      for (int r = 0; r < 4; ++r) {
        const float* ir = &Ilds[rbase + r][txx8];
        const float4 A0 = *(const float4*)&ir[0];
        const float4 A1 = *(const float4*)&ir[4];
        const float2 A2 = *(const float2*)&ir[8];
        const float av[10] = {A0.x,A0.y,A0.z,A0.w,A1.x,A1.y,A1.z,A1.w,A2.x,A2.y};
        if (r < 3) {            // output yy=0, dy=r  (dy ascends with r)
          #pragma unroll
          for (int dx = 0; dx < 3; ++dx) {
            const float4 w = wt[r * 3 + dx];
            const float wk[4] = {w.x, w.y, w.z, w.w};
            #pragma unroll
            for (int k = 0; k < 4; ++k)
              #pragma unroll
              for (int x = 0; x < 8; ++x)
                acc[k][0][x] += wk[k] * av[dx + x];
          }
        }
        if (r >= 1) {           // output yy=1, dy=r-1 (dy ascends with r)
          #pragma unroll
          for (int dx = 0; dx < 3; ++dx) {
            const float4 w = wt[(r - 1) * 3 + dx];
            const float wk[4] = {w.x, w.y, w.z, w.w};
            #pragma unroll
            for (int k = 0; k < 4; ++k)
              #pragma unroll
              for (int x = 0; x < 8; ++x)
                acc[k][1][x] += wk[k] * av[dx + x];
          }
        }
      }
    }
  }
  #pragma unroll
  for (int k = 0; k < 4; ++k) {
    const int ko = ko0 + tk4 + k;
    const float bv = bias[ko];
    #pragma unroll
    for (int yy = 0; yy < 2; ++yy) {
      const int y = ty0 + tyy2 + yy;
      float4 v0, v1;
      v0.x = fmaxf(acc[k][yy][0] + bv, 0.f);
      v0.y = fmaxf(acc[k][yy][1] + bv, 0.f);
      v0.z = fmaxf(acc[k][yy][2] + bv, 0.f);
      v0.w = fmaxf(acc[k][yy][3] + bv, 0.f);
      v1.x = fmaxf(acc[k][yy][4] + bv, 0.f);
      v1.y = fmaxf(acc[k][yy][5] + bv, 0.f);
      v1.z = fmaxf(acc[k][yy][6] + bv, 0.f);
      v1.w = fmaxf(acc[k][yy][7] + bv, 0.f);
      float* op = &out[(((size_t)b * NC + ko) << 12) + y * 64 + txx8];
      *(float4*)&op[0] = v0;
      *(float4*)&op[4] = v1;
    }
  }
}

// ---------------- 1x1 heads: 6 groups of 9 outputs, 2 positions/thread ----------------
// Channel-ascending accumulation order — bit-identical to head54_k.
__global__ __launch_bounds__(256) void head9_k(
    const float* __restrict__ conv, const float* __restrict__ Wcls,
    const float* __restrict__ bcls, const float* __restrict__ Wbbox,
    const float* __restrict__ bbbox, float* __restrict__ head) {
  __shared__ float Wl[9][68];
  const int b = blockIdx.z;
  const int g = blockIdx.y;                       // output group 0..5
  const int p0 = blockIdx.x * 512 + threadIdx.x;  // pos0; pos1 = p0 + 256
  const int tid = threadIdx.x;
  float acc0[9] = {}, acc1[9] = {};
  const float* cb = conv + ((size_t)b * NC << 12);
  for (int c0 = 0; c0 < NC; c0 += 64) {
    __syncthreads();
    for (int e = tid; e < 9 * 64; e += 256) {
      int o = e >> 6; int c = e & 63;
      int go = g * 9 + o;
      Wl[o][c] = (go < 18) ? Wcls[go * 512 + c0 + c] : Wbbox[(go - 18) * 512 + c0 + c];
    }
    __syncthreads();
    #pragma unroll 4
    for (int c = 0; c < 64; c += 4) {
      float v00 = cb[((size_t)(c0 + c + 0) << 12) + p0];
      float v01 = cb[((size_t)(c0 + c + 1) << 12) + p0];
      float v02 = cb[((size_t)(c0 + c + 2) << 12) + p0];
      float v03 = cb[((size_t)(c0 + c + 3) << 12) + p0];
      float v10 = cb[((size_t)(c0 + c + 0) << 12) + p0 + 256];
      float v11 = cb[((size_t)(c0 + c + 1) << 12) + p0 + 256];
      float v12 = cb[((size_t)(c0 + c + 2) << 12) + p0 + 256];
      float v13 = cb[((size_t)(c0 + c + 3) << 12) + p0 + 256];
      #pragma unroll
      for (int o = 0; o < 9; ++o) {
        const float4 w = *(const float4*)&Wl[o][c];
        acc0[o] += w.x * v00; acc0[o] += w.y * v01; acc0[o] += w.z * v02; acc0[o] += w.w * v03;
        acc1[o] += w.x * v10; acc1[o] += w.y * v11; acc1[o] += w.z * v12; acc1[o] += w.w * v13;
      }
    }
  }
  #pragma unroll
  for (int o = 0; o < 9; ++o) {
    int go = g * 9 + o;
    float bv = (go < 18) ? bcls[go] : bbbox[go - 18];
    head[(((size_t)b * 54 + go) << 12) + p0]       = acc0[o] + bv;
    head[(((size_t)b * 54 + go) << 12) + p0 + 256] = acc1[o] + bv;
  }
}

// ---------------- score + box decode + clip + LDS histogram ----------------
// NANCH % 256 == 0, so each block lies entirely in one batch.
__global__ __launch_bounds__(256) void decode_k(
    const float* __restrict__ head, const float* __restrict__ im_info,
    float* __restrict__ boxes, unsigned* __restrict__ skeys, unsigned* __restrict__ hist) {
  __shared__ unsigned hl[4096];
  const int tid = threadIdx.x;
  #pragma unroll
  for (int i = 0; i < 16; ++i) hl[tid + i * 256] = 0u;
  __syncthreads();
  int t = blockIdx.x * 256 + tid;
  int b = t / NANCH; int n = t - b * NANCH;
  int a = n % 9; int pos = n / 9;
  int x = pos & 63; int y = pos >> 6;
  const float* hb = head + ((size_t)b * 54 << 12);
  float s0 = hb[(a << 12) + pos];
  float s1 = hb[((9 + a) << 12) + pos];
  float m = fmaxf(s0, s1);
  float e0 = expf(s0 - m), e1 = expf(s1 - m);
  float score = e1 / (e0 + e1);
  int dbase = 18 + a * 4;
  float d0 = hb[((dbase + 0) << 12) + pos];
  float d1 = hb[((dbase + 1) << 12) + pos];
  float d2 = hb[((dbase + 2) << 12) + pos];
  float d3 = hb[((dbase + 3) << 12) + pos];
  float sx = x * 16.f, sy = y * 16.f;
  float ax1 = A9c[a][0] + sx, ay1 = A9c[a][1] + sy;
  float ax2 = A9c[a][2] + sx, ay2 = A9c[a][3] + sy;
  float aw = ax2 - ax1 + 1.f, ah = ay2 - ay1 + 1.f;
  float acx = ax1 + 0.5f * aw, acy = ay1 + 0.5f * ah;
  float pcx = d0 * aw + acx, pcy = d1 * ah + acy;
  float pw = expf(d2) * aw, ph = expf(d3) * ah;
  float imh = im_info[b * 3 + 0], imw = im_info[b * 3 + 1];
  float x1 = fminf(fmaxf(pcx - 0.5f * pw, 0.f), imw - 1.f);
  float y1 = fminf(fmaxf(pcy - 0.5f * ph, 0.f), imh - 1.f);
  float x2 = fminf(fmaxf(pcx + 0.5f * pw, 0.f), imw - 1.f);
  float y2 = fminf(fmaxf(pcy + 0.5f * ph, 0.f), imh - 1.f);
  *(float4*)&boxes[(size_t)t * 4] = make_float4(x1, y1, x2, y2);
  unsigned key = __float_as_uint(score);  // score>0 -> bits order == value order
  skeys[t] = key;
  atomicAdd(&hl[key >> 20], 1u);
  __syncthreads();
  // merge non-zero bins to global (scores cluster -> few non-zero bins per block)
  #pragma unroll
  for (int i = 0; i < 16; ++i) {
    unsigned c = hl[tid + i * 256];
    if (c) atomicAdd(&hist[b * 4096 + tid + i * 256], c);
  }
}

// ---------------- threshold select (2-level radix on float bits) ----------------
__global__ __launch_bounds__(256) void scan_hist_k(const unsigned* __restrict__ hist,
                                                  unsigned* __restrict__ misc) {
  int b = blockIdx.x;
  const unsigned* h = hist + b * 4096;
  __shared__ unsigned csum[256];
  int tid = threadIdx.x;
  unsigned s = 0;
  #pragma unroll
  for (int i = 0; i < 16; ++i) s += h[tid * 16 + i];
  csum[tid] = s;
  __syncthreads();
  if (tid == 0) {
    unsigned cum = 0; int chunk = 0;
    for (int c = 255; c >= 0; --c) {
      if (cum + csum[c] >= (unsigned)PRE_TOPN) { chunk = c; break; }
      cum += csum[c];
    }
    unsigned t1 = chunk * 16, cumAbove = cum;
    for (int i = 15; i >= 0; --i) {
      unsigned cnt = h[chunk * 16 + i];
      if (cum + cnt >= (unsigned)PRE_TOPN) { t1 = chunk * 16 + i; cumAbove = cum; break; }
      cum += cnt;
    }
    misc[b] = t1;          // boundary bin (top 12 bits)
    misc[4 + b] = cumAbove;
  }
}

__global__ __launch_bounds__(256) void hist2_k(const unsigned* __restrict__ skeys,
                                              const unsigned* __restrict__ misc,
                                              unsigned* __restrict__ hist2) {
  int t = blockIdx.x * 256 + threadIdx.x;
  if (t >= NB * NANCH) return;
  int b = t / NANCH;
  unsigned key = skeys[t];
  if ((key >> 20) == misc[b]) atomicAdd(&hist2[b * 256 + ((key >> 12) & 255u)], 1u);
}

__global__ void scan2_k(const unsigned* __restrict__ hist2, unsigned* __restrict__ misc) {
  int b = blockIdx.x;
  if (threadIdx.x != 0) return;
  unsigned cum = misc[4 + b];
  unsigned t1 = misc[b];
  unsigned T2 = t1 << 20;
  for (int s = 255; s >= 0; --s) {
    unsigned c = hist2[b * 256 + s];
    if (cum + c >= (unsigned)PRE_TOPN) { T2 = (t1 << 20) | ((unsigned)s << 12); break; }
    cum += c;
  }
  misc[8 + b] = T2;
}

// ---------------- compact: wave-aggregated atomic ----------------
__global__ __launch_bounds__(256) void compact_k(const unsigned* __restrict__ skeys,
                                                unsigned* __restrict__ misc,
                                                unsigned* __restrict__ ckey,
                                                unsigned* __restrict__ cidx) {
  int t = blockIdx.x * 256 + threadIdx.x;
  int b = t / NANCH; int n = t - b * NANCH;   // b uniform per wave (NANCH % 64 == 0)
  unsigned key = skeys[t];
  bool pred = key >= misc[8 + b];
  unsigned long long mball = __ballot(pred);
  int lane = threadIdx.x & 63;
  unsigned cnt = (unsigned)__popcll(mball);
  unsigned base = 0;
  if (lane == 0 && cnt) base = atomicAdd(&misc[12 + b], cnt);
  base = (unsigned)__shfl((int)base, 0, 64);
  if (pred) {
    unsigned p = base + (unsigned)__popcll(mball & ((1ull << lane) - 1ull));
    if (p < (unsigned)CAND_CAP) {
      ckey[(size_t)b * CAND_CAP + p] = key;
      cidx[(size_t)b * CAND_CAP + p] = (unsigned)n;
    }
  }
}

// ---------------- exact rank sort of candidates (desc score, asc index) ----------------
__global__ __launch_bounds__(256) void rank_scatter_k(
    const unsigned* __restrict__ ckey, const unsigned* __restrict__ cidx,
    const unsigned* __restrict__ misc, const float* __restrict__ boxes,
    float* __restrict__ sbox) {
  const int b = blockIdx.y;
  const int K = min((int)misc[12 + b], CAND_CAP);
  const int i = blockIdx.x * 256 + threadIdx.x;
  unsigned mykey = 0, myidx = 0;
  const bool active = i < K;
  if (active) {
    mykey = ckey[(size_t)b * CAND_CAP + i];
    myidx = cidx[(size_t)b * CAND_CAP + i];
  }
  int rank = 0;
  __shared__ unsigned skey[1024];
  __shared__ unsigned sidx[1024];
  for (int c0 = 0; c0 < K; c0 += 1024) {
    int n = min(1024, K - c0);
    __syncthreads();
    for (int e = threadIdx.x; e < n; e += 256) {
      skey[e] = ckey[(size_t)b * CAND_CAP + c0 + e];
      sidx[e] = cidx[(size_t)b * CAND_CAP + c0 + e];
    }
    __syncthreads();
    if (active) {
      for (int j = 0; j < n; ++j) {
        unsigned kj = skey[j];
        rank += (kj > mykey) || (kj == mykey && sidx[j] < myidx);
      }
    }
  }
  if (active && rank < PRE_TOPN) {
    float4 bx = *(const float4*)&boxes[((size_t)b * NANCH + myidx) * 4];
    *(float4*)&sbox[((size_t)b * PRE_TOPN + rank) * 4] = bx;
  }
}

// ---------------- IoU suppression bit-matrix: mask[b][i][w] bit q = (iou(i, w*64+q) > 0.7) --
__global__ __launch_bounds__(256) void iou_mask_k(const float* __restrict__ sbox,
                                                  unsigned long long* __restrict__ mask) {
  __shared__ float4 jb[3008];  // 48 KiB j-tile
  __shared__ float4 ib[32];    // i-tile
  const int b  = blockIdx.z;
  const int i0 = blockIdx.y * 32;
  const int w0 = blockIdx.x * 47;
  const int j0 = w0 * 64;
  const int nj = min(3008, PRE_TOPN - j0);
  const int tid = threadIdx.x;
  const float4* S = (const float4*)(sbox + (size_t)b * PRE_TOPN * 4);
  for (int e = tid; e < nj; e += 256) jb[e] = S[j0 + e];
  if (tid < 32 && i0 + tid < PRE_TOPN) ib[tid] = S[i0 + tid];
  __syncthreads();
  for (int idx = tid; idx < 32 * 47; idx += 256) {
    const int il = idx / 47, wl = idx - il * 47;
    const int i = i0 + il;
    if (i >= PRE_TOPN) continue;
    const float4 p = ib[il];
    const float parea = (p.z - p.x + 1.f) * (p.w - p.y + 1.f);
    unsigned long long m = 0;
    const int jb0 = wl * 64;
    #pragma unroll 8
    for (int q = 0; q < 64; ++q) {
      const int j = jb0 + q;   // j <= 46*64+63 = 3007 < 3008: always in-bounds
      const float4 qb = jb[j];
      float xx1 = fmaxf(p.x, qb.x), yy1 = fmaxf(p.y, qb.y);
      float xx2 = fminf(p.z, qb.z), yy2 = fminf(p.w, qb.w);
      float inter = fmaxf(xx2 - xx1 + 1.f, 0.f) * fmaxf(yy2 - yy1 + 1.f, 0.f);
      float area = (qb.z - qb.x + 1.f) * (qb.w - qb.y + 1.f);
      float iou = inter / (parea + area - inter);
      if (iou > 0.7f && j < nj) m |= (1ull << q);
    }
    mask[((size_t)b * PRE_TOPN + i) * MROW + w0 + wl] = m;
  }
}

// ---------------- wave-synchronous greedy pick: valid bitset in VGPRs ----------------
__device__ inline unsigned long long shfl_u64(unsigned long long v, int src) {
  int lo = __shfl((int)(unsigned)v, src, 64);
  int hi = __shfl((int)(unsigned)(v >> 32), src, 64);
  return ((unsigned long long)(unsigned)hi << 32) | (unsigned)lo;
}

__global__ __launch_bounds__(64) void nms_pick_k(const float* __restrict__ sbox,
                                                 const unsigned long long* __restrict__ mask,
                                                 float* __restrict__ out) {
  const int b = blockIdx.x;
  const int lane = threadIdx.x;
  unsigned long long va = ~0ull;
  unsigned long long vb = (lane < 29) ? ~0ull : (lane == 29 ? ((1ull << 48) - 1ull) : 0ull);
  const float* Bb = sbox + (size_t)b * PRE_TOPN * 4;
  float* O = out + (size_t)b * POST_TOPN * 5;
  int done = POST_TOPN;
  for (int it = 0; it < POST_TOPN; ++it) {
    unsigned long long ba = __ballot(va != 0ull);
    unsigned long long bb = __ballot(vb != 0ull);
    int w; unsigned long long word;
    if (ba) {
      w = __ffsll((long long)ba) - 1;
      word = shfl_u64(va, w);
    } else if (bb) {
      w = __ffsll((long long)bb) - 1;
      word = shfl_u64(vb, w);
      w += 64;
    } else { done = it; break; }
    const int i = (w << 6) + __ffsll((long long)word) - 1;
    const unsigned long long* row = mask + ((size_t)b * PRE_TOPN + i) * MROW;
    unsigned long long ra = row[lane];
    unsigned long long rb = (lane < 30) ? row[64 + lane] : 0ull;
    if (lane < 4) O[it * 5 + 1 + lane] = Bb[(size_t)i * 4 + lane];
    if (lane == 4) O[it * 5] = (float)b;
    va &= ~ra;
    vb &= ~rb;
  }
  for (int e = lane; e < (POST_TOPN - done) * 5; e += 64) {
    int r = done + e / 5; int c = e - (e / 5) * 5;
    O[r * 5 + c] = (c == 0) ? (float)b : 0.f;
  }
}

// ---------------- launch ----------------
extern "C" void kernel_launch(void* const* d_in, const int* in_sizes, int n_in,
                              void* d_out, int out_size, void* d_ws, size_t ws_size,
                              hipStream_t stream) {
  const float* base_feat = (const float*)d_in[0];
  const float* im_info   = (const float*)d_in[1];
  const float* W_conv    = (const float*)d_in[4];
  const float* b_conv    = (const float*)d_in[5];
  const float* W_cls     = (const float*)d_in[6];
  const float* b_cls     = (const float*)d_in[7];
  const float* W_bbox    = (const float*)d_in[8];
  const float* b_bbox    = (const float*)d_in[9];
  float* out = (float*)d_out;
  char* ws = (char*)d_ws;

  float*    Wt    = (float*)(ws + OFF_WT);
  float*    conv  = (float*)(ws + OFF_CONV);
  unsigned long long* mask = (unsigned long long*)(ws + OFF_MASK);  // overlays conv (dead after heads)
  float*    head  = (float*)(ws + OFF_HEAD);
  unsigned* skeys = (unsigned*)(ws + OFF_SKEY);
  float*    boxes = (float*)(ws + OFF_BOX);
  unsigned* hist  = (unsigned*)(ws + OFF_HIST);
  unsigned* hist2 = (unsigned*)(ws + OFF_HIST2);
  unsigned* misc  = (unsigned*)(ws + OFF_MISC);
  unsigned* ckey  = (unsigned*)(ws + OFF_CKEY);
  unsigned* cidx  = (unsigned*)(ws + OFF_CIDX);
  float*    sbox  = (float*)(ws + OFF_SBOX);

  // zero hist + hist2 + misc (contiguous)
  hipMemsetAsync(ws + OFF_HIST, 0, 65536 + 4096 + 256, stream);

  wtrans_k<<<(512 * 512 * 9 + 255) / 256, 256, 0, stream>>>(W_conv, Wt);
  conv3x3_relu_k<<<dim3(16, 16, 4), 128, 0, stream>>>(base_feat, Wt, b_conv, conv);
  head9_k<<<dim3(8, 6, 4), 256, 0, stream>>>(conv, W_cls, b_cls, W_bbox, b_bbox, head);
  decode_k<<<(NB * NANCH) / 256, 256, 0, stream>>>(head, im_info, boxes, skeys, hist);
  scan_hist_k<<<4, 256, 0, stream>>>(hist, misc);
  hist2_k<<<(NB * NANCH) / 256, 256, 0, stream>>>(skeys, misc, hist2);
  scan2_k<<<4, 64, 0, stream>>>(hist2, misc);
  compact_k<<<(NB * NANCH) / 256, 256, 0, stream>>>(skeys, misc, ckey, cidx);
  rank_scatter_k<<<dim3(CAND_CAP / 256, 4), 256, 0, stream>>>(ckey, cidx, misc, boxes, sbox);
  iou_mask_k<<<dim3(2, 188, 4), 256, 0, stream>>>(sbox, mask);
  nms_pick_k<<<4, 64, 0, stream>>>(sbox, mask, out);
}

// Round 8
// 1858.354 us; speedup vs baseline: 1.2163x; 1.2163x over previous
//
#include <hip/hip_runtime.h>
#include <math.h>

// ---------------- problem constants ----------------
constexpr int NB = 4;            // batch
constexpr int NC = 512;          // channels
constexpr int NH = 64, NW = 64;  // spatial
constexpr int NPOS = NH * NW;        // 4096
constexpr int NANCH = NPOS * 9;      // 36864 anchors/batch
constexpr int PRE_TOPN = 6000;
constexpr int POST_TOPN = 300;
constexpr int CAND_CAP = 40960;
constexpr int MROW = 96;             // mask row stride in u64 (94 used)

// anchors for base_size=16, ratios {0.5,1,2}, scales {8,16,32} (verified vs numpy)
__device__ __constant__ float A9c[9][4] = {
  {-84.f,-40.f,99.f,55.f},   {-176.f,-88.f,191.f,103.f}, {-360.f,-184.f,375.f,199.f},
  {-56.f,-56.f,71.f,71.f},   {-120.f,-120.f,135.f,135.f},{-248.f,-248.f,263.f,263.f},
  {-36.f,-80.f,51.f,95.f},   {-80.f,-168.f,95.f,183.f},  {-168.f,-344.f,183.f,359.f}};

// ---------------- ws layout (bytes) ----------------
constexpr size_t OFF_WT    = 0;                       // 512*512*9*4      = 9,437,184
constexpr size_t OFF_CONV  = 9437184;                 // 4*512*4096*4     = 33,554,432 (reused as IoU mask after heads)
constexpr size_t OFF_MASK  = OFF_CONV;                // 4*6000*96*8      = 18,432,000 (overlay)
constexpr size_t OFF_HEAD  = 42991616;                // 4*54*4096*4      = 3,538,944
constexpr size_t OFF_SKEY  = 46530560;                // 4*36864*4        = 589,824
constexpr size_t OFF_BOX   = 47120384;                // 4*36864*4*4      = 2,359,296
constexpr size_t OFF_HIST  = 49479680;                // 4*4096*4         = 65,536
constexpr size_t OFF_HIST2 = 49545216;                // 4*256*4          = 4,096 (unused, kept for layout)
constexpr size_t OFF_MISC  = 49549312;                // 256
constexpr size_t OFF_CKEY  = 49549568;                // 4*40960*4        = 655,360
constexpr size_t OFF_CIDX  = 50204928;                // 4*40960*4        = 655,360
constexpr size_t OFF_SBOX  = 50860288;                // 4*6000*4*4       = 384,000
// total ≈ 51.2 MB

// ---------------- weight transpose via LDS tile: W[ko][c][tap] -> Wt[c*9+tap][ko] ------
__global__ __launch_bounds__(256) void wtrans_k(const float* __restrict__ Wc,
                                               float* __restrict__ Wt) {
  __shared__ float tile[64][65];
  const int r0 = blockIdx.x * 64;   // r = c*9+tap block (4608/64 = 72)
  const int k0 = blockIdx.y * 64;   // ko block (512/64 = 8)
  const int tid = threadIdx.x;
  const int col = tid & 63, row4 = tid >> 6;
  for (int kk = row4; kk < 64; kk += 4)
    tile[kk][col] = Wc[(size_t)(k0 + kk) * 4608 + r0 + col];
  __syncthreads();
  for (int rr = row4; rr < 64; rr += 4)
    Wt[(size_t)(r0 + rr) * 512 + k0 + col] = tile[col][rr];
}

// ---------------- 3x3 conv + bias + relu (fp32, 4ko x 8x per thread) ----------------
// Block: 32 ko x 4 y x 64 x (full row). Grid (16,16,4) = 1024 blocks = 4/CU.
// EXACT R6 kernel (best measured: 1183 us). Accumulation order c asc, dy asc, dx asc —
// bit-identical selection.
__global__ __launch_bounds__(256, 4) void conv3x3_relu_k(
    const float* __restrict__ in, const float* __restrict__ Wt,
    const float* __restrict__ bias, float* __restrict__ out) {
  __shared__ float Ilds[48][68];      // row = cc*6 + yy (8 c x 6 y incl halo); 66 cols used
  __shared__ float Wlds[8][9][32];    // c, tap, ko
  const int ko0 = blockIdx.x * 32;    // 16 ko-blocks
  const int ty0 = blockIdx.y * 4;     // 16 y-tiles
  const int b   = blockIdx.z;
  const int tid = threadIdx.x;
  const int tk4  = (tid & 7) * 4;     // 4 kout per thread
  const int tyy  = (tid >> 3) & 3;    // row within tile
  const int txx8 = (tid >> 5) * 8;    // 8 x per thread

  float acc[4][8] = {};
  const float* inb = in + (size_t)b * NC * NPOS;

  for (int c0 = 0; c0 < NC; c0 += 8) {
    __syncthreads();
    // stage input: col j holds gx = j-1. Main cols 0..63 (gx -1..62):
    for (int e = tid; e < 48 * 64; e += 256) {
      int r = e >> 6, xx = e & 63;
      int cc = r / 6; int yy = r - cc * 6;
      int gy = ty0 + yy - 1, gx = xx - 1;
      float v = 0.f;
      if ((unsigned)gy < 64u && (unsigned)gx < 64u)
        v = inb[(size_t)(c0 + cc) * NPOS + gy * 64 + gx];
      Ilds[r][xx] = v;
    }
    // halo cols 64,65 (gx 63,64):
    if (tid < 96) {
      int r = tid >> 1, j = tid & 1;
      int cc = r / 6; int yy = r - cc * 6;
      int gy = ty0 + yy - 1, gx = 63 + j;
      float v = 0.f;
      if ((unsigned)gy < 64u && gx < 64)
        v = inb[(size_t)(c0 + cc) * NPOS + gy * 64 + gx];
      Ilds[r][64 + j] = v;
    }
    // stage weights 8 x 9 x 32 = 2304 elems; destination linear in e
    for (int e = tid; e < 8 * 9 * 32; e += 256) {
      int ko = e & 31; int r = e >> 5; int tap = r % 9; int cc = r / 9;
      ((float*)Wlds)[e] = Wt[(size_t)(c0 + cc) * 4608 + tap * 512 + ko0 + ko];
    }
    __syncthreads();
    #pragma unroll 2
    for (int cc = 0; cc < 8; ++cc) {
      #pragma unroll
      for (int dy = 0; dy < 3; ++dy) {
        const float* ir = &Ilds[cc * 6 + tyy + dy][txx8];
        const float4 A0 = *(const float4*)&ir[0];
        const float4 A1 = *(const float4*)&ir[4];
        const float2 A2 = *(const float2*)&ir[8];
        const float av[10] = {A0.x,A0.y,A0.z,A0.w,A1.x,A1.y,A1.z,A1.w,A2.x,A2.y};
        #pragma unroll
        for (int dx = 0; dx < 3; ++dx) {
          const float4 w = *(const float4*)&Wlds[cc][dy * 3 + dx][tk4];
          const float wk[4] = {w.x, w.y, w.z, w.w};
          #pragma unroll
          for (int k = 0; k < 4; ++k) {
            #pragma unroll
            for (int x = 0; x < 8; ++x) {
              acc[k][x] += wk[k] * av[dx + x];
            }
          }
        }
      }
    }
  }
  const int y = ty0 + tyy;
  #pragma unroll
  for (int k = 0; k < 4; ++k) {
    int ko = ko0 + tk4 + k;
    float bv = bias[ko];
    float4 v0, v1;
    v0.x = fmaxf(acc[k][0] + bv, 0.f);
    v0.y = fmaxf(acc[k][1] + bv, 0.f);
    v0.z = fmaxf(acc[k][2] + bv, 0.f);
    v0.w = fmaxf(acc[k][3] + bv, 0.f);
    v1.x = fmaxf(acc[k][4] + bv, 0.f);
    v1.y = fmaxf(acc[k][5] + bv, 0.f);
    v1.z = fmaxf(acc[k][6] + bv, 0.f);
    v1.w = fmaxf(acc[k][7] + bv, 0.f);
    float* op = &out[(((size_t)b * NC + ko) << 12) + y * 64 + txx8];
    *(float4*)&op[0] = v0;
    *(float4*)&op[4] = v1;
  }
}

// ---------------- 1x1 heads: 6 groups of 9 outputs, 2 positions/thread ----------------
// Channel-ascending accumulation order — bit-identical to head54_k.
__global__ __launch_bounds__(256) void head9_k(
    const float* __restrict__ conv, const float* __restrict__ Wcls,
    const float* __restrict__ bcls, const float* __restrict__ Wbbox,
    const float* __restrict__ bbbox, float* __restrict__ head) {
  __shared__ float Wl[9][68];
  const int b = blockIdx.z;
  const int g = blockIdx.y;                       // output group 0..5
  const int p0 = blockIdx.x * 512 + threadIdx.x;  // pos0; pos1 = p0 + 256
  const int tid = threadIdx.x;
  float acc0[9] = {}, acc1[9] = {};
  const float* cb = conv + ((size_t)b * NC << 12);
  for (int c0 = 0; c0 < NC; c0 += 64) {
    __syncthreads();
    for (int e = tid; e < 9 * 64; e += 256) {
      int o = e >> 6; int c = e & 63;
      int go = g * 9 + o;
      Wl[o][c] = (go < 18) ? Wcls[go * 512 + c0 + c] : Wbbox[(go - 18) * 512 + c0 + c];
    }
    __syncthreads();
    #pragma unroll 4
    for (int c = 0; c < 64; c += 4) {
      float v00 = cb[((size_t)(c0 + c + 0) << 12) + p0];
      float v01 = cb[((size_t)(c0 + c + 1) << 12) + p0];
      float v02 = cb[((size_t)(c0 + c + 2) << 12) + p0];
      float v03 = cb[((size_t)(c0 + c + 3) << 12) + p0];
      float v10 = cb[((size_t)(c0 + c + 0) << 12) + p0 + 256];
      float v11 = cb[((size_t)(c0 + c + 1) << 12) + p0 + 256];
      float v12 = cb[((size_t)(c0 + c + 2) << 12) + p0 + 256];
      float v13 = cb[((size_t)(c0 + c + 3) << 12) + p0 + 256];
      #pragma unroll
      for (int o = 0; o < 9; ++o) {
        const float4 w = *(const float4*)&Wl[o][c];
        acc0[o] += w.x * v00; acc0[o] += w.y * v01; acc0[o] += w.z * v02; acc0[o] += w.w * v03;
        acc1[o] += w.x * v10; acc1[o] += w.y * v11; acc1[o] += w.z * v12; acc1[o] += w.w * v13;
      }
    }
  }
  #pragma unroll
  for (int o = 0; o < 9; ++o) {
    int go = g * 9 + o;
    float bv = (go < 18) ? bcls[go] : bbbox[go - 18];
    head[(((size_t)b * 54 + go) << 12) + p0]       = acc0[o] + bv;
    head[(((size_t)b * 54 + go) << 12) + p0 + 256] = acc1[o] + bv;
  }
}

// ---------------- score + box decode + clip + LDS histogram (pos-major) ----------------
// One thread per position; reads all 54 channels coalesced (lanes = consecutive pos).
// Grid 64 blocks x 256 threads = 16384 = NB*NPOS; each block in one batch (4096%256==0).
__global__ __launch_bounds__(256) void decode_k(
    const float* __restrict__ head, const float* __restrict__ im_info,
    float* __restrict__ boxes, unsigned* __restrict__ skeys, unsigned* __restrict__ hist) {
  __shared__ unsigned hl[4096];
  const int tid = threadIdx.x;
  #pragma unroll
  for (int i = 0; i < 16; ++i) hl[tid + i * 256] = 0u;
  __syncthreads();
  const int p = blockIdx.x * 256 + tid;
  const int b = p >> 12; const int pos = p & 4095;
  const int x = pos & 63; const int y = pos >> 6;
  const float* hb = head + ((size_t)b * 54 << 12);
  const float imh = im_info[b * 3 + 0], imw = im_info[b * 3 + 1];
  float s[18];
  #pragma unroll
  for (int o = 0; o < 18; ++o) s[o] = hb[(o << 12) + pos];
  float d[36];
  #pragma unroll
  for (int o = 0; o < 36; ++o) d[o] = hb[((18 + o) << 12) + pos];
  const float sx = x * 16.f, sy = y * 16.f;
  #pragma unroll
  for (int a = 0; a < 9; ++a) {
    const float s0 = s[a], s1 = s[9 + a];
    const float m = fmaxf(s0, s1);
    const float e0 = expf(s0 - m), e1 = expf(s1 - m);
    const float score = e1 / (e0 + e1);
    const float d0 = d[a * 4 + 0], d1 = d[a * 4 + 1];
    const float d2 = d[a * 4 + 2], d3 = d[a * 4 + 3];
    const float ax1 = A9c[a][0] + sx, ay1 = A9c[a][1] + sy;
    const float ax2 = A9c[a][2] + sx, ay2 = A9c[a][3] + sy;
    const float aw = ax2 - ax1 + 1.f, ah = ay2 - ay1 + 1.f;
    const float acx = ax1 + 0.5f * aw, acy = ay1 + 0.5f * ah;
    const float pcx = d0 * aw + acx, pcy = d1 * ah + acy;
    const float pw = expf(d2) * aw, ph = expf(d3) * ah;
    const float x1 = fminf(fmaxf(pcx - 0.5f * pw, 0.f), imw - 1.f);
    const float y1 = fminf(fmaxf(pcy - 0.5f * ph, 0.f), imh - 1.f);
    const float x2 = fminf(fmaxf(pcx + 0.5f * pw, 0.f), imw - 1.f);
    const float y2 = fminf(fmaxf(pcy + 0.5f * ph, 0.f), imh - 1.f);
    const int n = pos * 9 + a;
    *(float4*)&boxes[((size_t)b * NANCH + n) * 4] = make_float4(x1, y1, x2, y2);
    const unsigned key = __float_as_uint(score);  // score>0 -> bits order == value order
    skeys[(size_t)b * NANCH + n] = key;
    atomicAdd(&hl[key >> 20], 1u);
  }
  __syncthreads();
  #pragma unroll
  for (int i = 0; i < 16; ++i) {
    unsigned c = hl[tid + i * 256];
    if (c) atomicAdd(&hist[b * 4096 + tid + i * 256], c);
  }
}

// ---------------- fused threshold select + compact (one block per batch) ----------------
// Replaces scan_hist_k + hist2_k + scan2_k + compact_k. LDS-resident fine histogram
// and serial scans; wave-aggregated LDS counter for compaction. Order within ckey
// differs from before but rank_scatter is order-independent.
__global__ __launch_bounds__(256) void select_k(
    const unsigned* __restrict__ skeys, const unsigned* __restrict__ hist,
    unsigned* __restrict__ misc, unsigned* __restrict__ ckey,
    unsigned* __restrict__ cidx) {
  const int b = blockIdx.x;
  const int tid = threadIdx.x;
  __shared__ unsigned csum[256];
  __shared__ unsigned hl2[256];
  __shared__ unsigned s_t1, s_cumAbove, s_T2, s_cnt;
  const unsigned* h = hist + b * 4096;
  unsigned s = 0;
  #pragma unroll
  for (int i = 0; i < 16; ++i) s += h[tid * 16 + i];
  csum[tid] = s;
  hl2[tid] = 0u;
  __syncthreads();
  if (tid == 0) {
    unsigned cum = 0; int chunk = 0;
    for (int c = 255; c >= 0; --c) {
      if (cum + csum[c] >= (unsigned)PRE_TOPN) { chunk = c; break; }
      cum += csum[c];
    }
    unsigned t1 = chunk * 16, cumAbove = cum;
    for (int i = 15; i >= 0; --i) {
      unsigned cnt = h[chunk * 16 + i];
      if (cum + cnt >= (unsigned)PRE_TOPN) { t1 = chunk * 16 + i; cumAbove = cum; break; }
      cum += cnt;
    }
    s_t1 = t1; s_cumAbove = cumAbove; s_cnt = 0u;
  }
  __syncthreads();
  const unsigned t1 = s_t1;
  const unsigned* sk = skeys + (size_t)b * NANCH;
  for (int t = tid; t < NANCH; t += 256) {
    unsigned key = sk[t];
    if ((key >> 20) == t1) atomicAdd(&hl2[(key >> 12) & 255u], 1u);
  }
  __syncthreads();
  if (tid == 0) {
    unsigned cum = s_cumAbove;
    unsigned T2 = t1 << 20;
    for (int ss = 255; ss >= 0; --ss) {
      unsigned c = hl2[ss];
      if (cum + c >= (unsigned)PRE_TOPN) { T2 = (t1 << 20) | ((unsigned)ss << 12); break; }
      cum += c;
    }
    s_T2 = T2;
  }
  __syncthreads();
  const unsigned T2 = s_T2;
  const int lane = tid & 63;
  for (int t = tid; t < NANCH; t += 256) {   // NANCH % 256 == 0: uniform trip count
    unsigned key = sk[t];
    bool pred = key >= T2;
    unsigned long long mb = __ballot(pred);
    unsigned base = 0;
    if (lane == 0) base = atomicAdd(&s_cnt, (unsigned)__popcll(mb));
    base = (unsigned)__shfl((int)base, 0, 64);
    if (pred) {
      unsigned pp = base + (unsigned)__popcll(mb & ((1ull << lane) - 1ull));
      if (pp < (unsigned)CAND_CAP) {
        ckey[(size_t)b * CAND_CAP + pp] = key;
        cidx[(size_t)b * CAND_CAP + pp] = (unsigned)t;
      }
    }
  }
  __syncthreads();
  if (tid == 0) misc[12 + b] = s_cnt;
}

// ---------------- exact rank sort of candidates (desc score, asc index) ----------------
__global__ __launch_bounds__(256) void rank_scatter_k(
    const unsigned* __restrict__ ckey, const unsigned* __restrict__ cidx,
    const unsigned* __restrict__ misc, const float* __restrict__ boxes,
    float* __restrict__ sbox) {
  const int b = blockIdx.y;
  const int K = min((int)misc[12 + b], CAND_CAP);
  const int i = blockIdx.x * 256 + threadIdx.x;
  unsigned mykey = 0, myidx = 0;
  const bool active = i < K;
  if (active) {
    mykey = ckey[(size_t)b * CAND_CAP + i];
    myidx = cidx[(size_t)b * CAND_CAP + i];
  }
  int rank = 0;
  __shared__ unsigned skey[1024];
  __shared__ unsigned sidx[1024];
  for (int c0 = 0; c0 < K; c0 += 1024) {
    int n = min(1024, K - c0);
    __syncthreads();
    for (int e = threadIdx.x; e < n; e += 256) {
      skey[e] = ckey[(size_t)b * CAND_CAP + c0 + e];
      sidx[e] = cidx[(size_t)b * CAND_CAP + c0 + e];
    }
    __syncthreads();
    if (active) {
      for (int j = 0; j < n; ++j) {
        unsigned kj = skey[j];
        rank += (kj > mykey) || (kj == mykey && sidx[j] < myidx);
      }
    }
  }
  if (active && rank < PRE_TOPN) {
    float4 bx = *(const float4*)&boxes[((size_t)b * NANCH + myidx) * 4];
    *(float4*)&sbox[((size_t)b * PRE_TOPN + rank) * 4] = bx;
  }
}

// ---------------- IoU suppression bit-matrix: mask[b][i][w] bit q = (iou(i, w*64+q) > 0.7) --
__global__ __launch_bounds__(256) void iou_mask_k(const float* __restrict__ sbox,
                                                  unsigned long long* __restrict__ mask) {
  __shared__ float4 jb[3008];  // 48 KiB j-tile
  __shared__ float4 ib[32];    // i-tile
  const int b  = blockIdx.z;
  const int i0 = blockIdx.y * 32;
  const int w0 = blockIdx.x * 47;
  const int j0 = w0 * 64;
  const int nj = min(3008, PRE_TOPN - j0);
  const int tid = threadIdx.x;
  const float4* S = (const float4*)(sbox + (size_t)b * PRE_TOPN * 4);
  for (int e = tid; e < nj; e += 256) jb[e] = S[j0 + e];
  if (tid < 32 && i0 + tid < PRE_TOPN) ib[tid] = S[i0 + tid];
  __syncthreads();
  for (int idx = tid; idx < 32 * 47; idx += 256) {
    const int il = idx / 47, wl = idx - il * 47;
    const int i = i0 + il;
    if (i >= PRE_TOPN) continue;
    const float4 p = ib[il];
    const float parea = (p.z - p.x + 1.f) * (p.w - p.y + 1.f);
    unsigned long long m = 0;
    const int jb0 = wl * 64;
    #pragma unroll 8
    for (int q = 0; q < 64; ++q) {
      const int j = jb0 + q;   // j <= 46*64+63 = 3007 < 3008: always in-bounds
      const float4 qb = jb[j];
      float xx1 = fmaxf(p.x, qb.x), yy1 = fmaxf(p.y, qb.y);
      float xx2 = fminf(p.z, qb.z), yy2 = fminf(p.w, qb.w);
      float inter = fmaxf(xx2 - xx1 + 1.f, 0.f) * fmaxf(yy2 - yy1 + 1.f, 0.f);
      float area = (qb.z - qb.x + 1.f) * (qb.w - qb.y + 1.f);
      float iou = inter / (parea + area - inter);
      if (iou > 0.7f && j < nj) m |= (1ull << q);
    }
    mask[((size_t)b * PRE_TOPN + i) * MROW + w0 + wl] = m;
  }
}

// ---------------- wave-synchronous greedy pick: valid bitset in VGPRs ----------------
__device__ inline unsigned long long shfl_u64(unsigned long long v, int src) {
  int lo = __shfl((int)(unsigned)v, src, 64);
  int hi = __shfl((int)(unsigned)(v >> 32), src, 64);
  return ((unsigned long long)(unsigned)hi << 32) | (unsigned)lo;
}

__global__ __launch_bounds__(64) void nms_pick_k(const float* __restrict__ sbox,
                                                 const unsigned long long* __restrict__ mask,
                                                 float* __restrict__ out) {
  const int b = blockIdx.x;
  const int lane = threadIdx.x;
  unsigned long long va = ~0ull;
  unsigned long long vb = (lane < 29) ? ~0ull : (lane == 29 ? ((1ull << 48) - 1ull) : 0ull);
  const float* Bb = sbox + (size_t)b * PRE_TOPN * 4;
  float* O = out + (size_t)b * POST_TOPN * 5;
  int done = POST_TOPN;
  for (int it = 0; it < POST_TOPN; ++it) {
    unsigned long long ba = __ballot(va != 0ull);
    unsigned long long bb = __ballot(vb != 0ull);
    int w; unsigned long long word;
    if (ba) {
      w = __ffsll((long long)ba) - 1;
      word = shfl_u64(va, w);
    } else if (bb) {
      w = __ffsll((long long)bb) - 1;
      word = shfl_u64(vb, w);
      w += 64;
    } else { done = it; break; }
    const int i = (w << 6) + __ffsll((long long)word) - 1;
    const unsigned long long* row = mask + ((size_t)b * PRE_TOPN + i) * MROW;
    unsigned long long ra = row[lane];
    unsigned long long rb = (lane < 30) ? row[64 + lane] : 0ull;
    if (lane < 4) O[it * 5 + 1 + lane] = Bb[(size_t)i * 4 + lane];
    if (lane == 4) O[it * 5] = (float)b;
    va &= ~ra;
    vb &= ~rb;
  }
  for (int e = lane; e < (POST_TOPN - done) * 5; e += 64) {
    int r = done + e / 5; int c = e - (e / 5) * 5;
    O[r * 5 + c] = (c == 0) ? (float)b : 0.f;
  }
}

// ---------------- launch ----------------
extern "C" void kernel_launch(void* const* d_in, const int* in_sizes, int n_in,
                              void* d_out, int out_size, void* d_ws, size_t ws_size,
                              hipStream_t stream) {
  const float* base_feat = (const float*)d_in[0];
  const float* im_info   = (const float*)d_in[1];
  const float* W_conv    = (const float*)d_in[4];
  const float* b_conv    = (const float*)d_in[5];
  const float* W_cls     = (const float*)d_in[6];
  const float* b_cls     = (const float*)d_in[7];
  const float* W_bbox    = (const float*)d_in[8];
  const float* b_bbox    = (const float*)d_in[9];
  float* out = (float*)d_out;
  char* ws = (char*)d_ws;

  float*    Wt    = (float*)(ws + OFF_WT);
  float*    conv  = (float*)(ws + OFF_CONV);
  unsigned long long* mask = (unsigned long long*)(ws + OFF_MASK);  // overlays conv (dead after heads)
  float*    head  = (float*)(ws + OFF_HEAD);
  unsigned* skeys = (unsigned*)(ws + OFF_SKEY);
  float*    boxes = (float*)(ws + OFF_BOX);
  unsigned* hist  = (unsigned*)(ws + OFF_HIST);
  unsigned* misc  = (unsigned*)(ws + OFF_MISC);
  unsigned* ckey  = (unsigned*)(ws + OFF_CKEY);
  unsigned* cidx  = (unsigned*)(ws + OFF_CIDX);
  float*    sbox  = (float*)(ws + OFF_SBOX);

  // zero hist (+ legacy hist2 region + misc; harmless, one memset)
  hipMemsetAsync(ws + OFF_HIST, 0, 65536 + 4096 + 256, stream);

  wtrans_k<<<dim3(72, 8), 256, 0, stream>>>(W_conv, Wt);
  conv3x3_relu_k<<<dim3(16, 16, 4), 256, 0, stream>>>(base_feat, Wt, b_conv, conv);
  head9_k<<<dim3(8, 6, 4), 256, 0, stream>>>(conv, W_cls, b_cls, W_bbox, b_bbox, head);
  decode_k<<<64, 256, 0, stream>>>(head, im_info, boxes, skeys, hist);
  select_k<<<4, 256, 0, stream>>>(skeys, hist, misc, ckey, cidx);
  rank_scatter_k<<<dim3(CAND_CAP / 256, 4), 256, 0, stream>>>(ckey, cidx, misc, boxes, sbox);
  iou_mask_k<<<dim3(2, 188, 4), 256, 0, stream>>>(sbox, mask);
  nms_pick_k<<<4, 64, 0, stream>>>(sbox, mask, out);
}

// Round 9
// 1188.716 us; speedup vs baseline: 1.9014x; 1.5633x over previous
//
#include <hip/hip_runtime.h>
#include <math.h>

// ---------------- problem constants ----------------
constexpr int NB = 4;            // batch
constexpr int NC = 512;          // channels
constexpr int NH = 64, NW = 64;  // spatial
constexpr int NPOS = NH * NW;        // 4096
constexpr int NANCH = NPOS * 9;      // 36864 anchors/batch
constexpr int PRE_TOPN = 6000;
constexpr int POST_TOPN = 300;
constexpr int CAND_CAP = 40960;
constexpr int MROW = 96;             // mask row stride in u64 (94 used)

typedef short short8_t __attribute__((ext_vector_type(8)));
typedef float f32x4_t __attribute__((ext_vector_type(4)));

// anchors for base_size=16, ratios {0.5,1,2}, scales {8,16,32} (verified vs numpy)
__device__ __constant__ float A9c[9][4] = {
  {-84.f,-40.f,99.f,55.f},   {-176.f,-88.f,191.f,103.f}, {-360.f,-184.f,375.f,199.f},
  {-56.f,-56.f,71.f,71.f},   {-120.f,-120.f,135.f,135.f},{-248.f,-248.f,263.f,263.f},
  {-36.f,-80.f,51.f,95.f},   {-80.f,-168.f,95.f,183.f},  {-168.f,-344.f,183.f,359.f}};

// ---------------- ws layout (bytes) ----------------
constexpr size_t OFF_WT2  = 0;          // 9*512*512*4  = 9,437,184 (fp32 W [tap][ko][c]; dead after conv)
constexpr size_t OFF_IT   = 9437184;    // 4*4096*512*4 = 33,554,432 (fp32 input [b][pos][c]; dead after conv)
constexpr size_t OFF_CONV = 42991616;   // 4*512*4096*4 = 33,554,432
constexpr size_t OFF_HIST = 76546048;   // 4*4096*4 = 65,536
constexpr size_t OFF_MISC = 76611584;   // 256
// overlays (written only after their host region is dead):
constexpr size_t OFF_MASK = OFF_IT;     // 4*6000*96*8 = 18,432,000 <= 33.5 MB (after conv)
constexpr size_t OFF_HEAD = 0;          // 3,538,944  (after conv, inside WT2)
constexpr size_t OFF_SKEY = 3538944;    // 589,824
constexpr size_t OFF_BOX  = 4128768;    // 2,359,296
constexpr size_t OFF_CKEY = 6488064;    // 655,360
constexpr size_t OFF_CIDX = 7143424;    // 655,360
constexpr size_t OFF_SBOX = 7798784;    // 384,000 -> end 8,182,784 < 9,437,184 OK
// total ws = 76,611,840 bytes

// ---------------- bf16 helpers (RNE) ----------------
__device__ inline unsigned short f2bf(float f) {
  unsigned u = __float_as_uint(f);
  unsigned r = u + 0x7fffu + ((u >> 16) & 1u);
  return (unsigned short)(r >> 16);
}
__device__ inline float bf2f(unsigned short h) { return __uint_as_float(((unsigned)h) << 16); }

// split 8 floats into hi/mid/lo bf16 (24 mantissa bits total)
__device__ inline void split8(const float4 A, const float4 B, short8_t& h, short8_t& m, short8_t& l) {
#define SPL(J, X) { unsigned short hh = f2bf(X); float fh = bf2f(hh); \
                    unsigned short mm = f2bf((X) - fh); float fm = bf2f(mm); \
                    unsigned short ll = f2bf((X) - fh - fm); \
                    h[J] = (short)hh; m[J] = (short)mm; l[J] = (short)ll; }
  SPL(0, A.x) SPL(1, A.y) SPL(2, A.z) SPL(3, A.w)
  SPL(4, B.x) SPL(5, B.y) SPL(6, B.z) SPL(7, B.w)
#undef SPL
}

// ---------------- W[ko][c][tap] -> Wt2[tap][ko][c] (fp32) ----------------
__global__ __launch_bounds__(256) void wtrans2_k(const float* __restrict__ Wc,
                                                float* __restrict__ Wt2) {
  int i = blockIdx.x * 256 + threadIdx.x;   // exact: 9*512*512 / 256 = 9216 blocks
  int tap = i >> 18;
  int rem = i & 262143;
  int ko = rem >> 9, c = rem & 511;
  Wt2[i] = Wc[(size_t)ko * 4608 + c * 9 + tap];
}

// ---------------- input [b][c][pos] -> It [b][pos][c] (fp32 transpose) ----------------
__global__ __launch_bounds__(256) void cvtI_k(const float* __restrict__ in,
                                              float* __restrict__ It) {
  __shared__ float T[64][65];
  const int b = blockIdx.z, c0 = blockIdx.y * 64, pos0 = blockIdx.x * 64;
  const int tid = threadIdx.x;
  for (int i = tid; i < 4096; i += 256) {
    int cc = i >> 6, pp = i & 63;
    T[cc][pp] = in[(((size_t)b * 512 + c0 + cc) << 12) + pos0 + pp];
  }
  __syncthreads();
  for (int i = tid; i < 4096; i += 256) {
    int pp = i >> 6, cc = i & 63;
    It[((((size_t)b << 12) + pos0 + pp) << 9) + c0 + cc] = T[cc][pp];
  }
}

// ---------------- conv3x3 + bias + relu via MFMA (bf16x3 split, 6 products) ----------------
// Block: 128 ko x 128 pos (2 y-rows), 4 waves; wave owns 2 ko-frags x 8 pos-frags.
// K ordered tap-major: for each 32-channel stage, loop 9 taps (K-step=32 per (stage,tap)).
// LDS XOR-swizzle (cgroup ^ (row&3)) keeps ds_read_b128 conflict-free.
__global__ __launch_bounds__(256, 2) void conv_mfma_k(
    const float* __restrict__ It, const float* __restrict__ Wt2,
    const float* __restrict__ bias, float* __restrict__ out) {
  __shared__ short Slds[3 * 264 * 32];   // [plane][r*66+xx][32c] 50,688 B
  __shared__ short Wl[3 * 128 * 32];     // [plane][ko][32c]     24,576 B
  const int tid = threadIdx.x;
  const int wave = tid >> 6, lane = tid & 63;
  const int lm = lane & 15, lg = lane >> 4;
  const int pos0 = blockIdx.x * 128;
  const int ko0  = blockIdx.y * 128;
  const int b    = blockIdx.z;
  const int y0   = pos0 >> 6;            // first of 2 output rows

  f32x4_t acc[2][8];
  #pragma unroll
  for (int f = 0; f < 2; ++f)
    #pragma unroll
    for (int p = 0; p < 8; ++p) acc[f][p] = (f32x4_t){0.f, 0.f, 0.f, 0.f};

  for (int c0 = 0; c0 < 512; c0 += 32) {
    __syncthreads();   // protect previous tap's Slds reads
    // ---- stage input: 264 slots (4 rows x 66 xx) x 32 c, fp32 -> 3 bf16 planes ----
    for (int i = tid; i < 264; i += 256) {
      int r = i / 66, xx = i - r * 66;
      int gy = y0 + r - 1, gx = xx - 1;
      bool ok = ((unsigned)gy < 64u) && ((unsigned)gx < 64u);
      float4 f0 = {}, f1 = {}, f2 = {}, f3 = {}, f4 = {}, f5 = {}, f6 = {}, f7 = {};
      if (ok) {
        const float4* gp = (const float4*)(It + ((((size_t)b << 12) + (gy << 6) + gx) << 9) + c0);
        f0 = gp[0]; f1 = gp[1]; f2 = gp[2]; f3 = gp[3];
        f4 = gp[4]; f5 = gp[5]; f6 = gp[6]; f7 = gp[7];
      }
      const int sw = xx & 3;
      char* drow = (char*)Slds + (i << 6);
      short8_t h, m, l;
      split8(f0, f1, h, m, l);
      *(short8_t*)(drow + ((0 ^ sw) << 4)) = h;
      *(short8_t*)(drow + 16896 + ((0 ^ sw) << 4)) = m;
      *(short8_t*)(drow + 33792 + ((0 ^ sw) << 4)) = l;
      split8(f2, f3, h, m, l);
      *(short8_t*)(drow + ((1 ^ sw) << 4)) = h;
      *(short8_t*)(drow + 16896 + ((1 ^ sw) << 4)) = m;
      *(short8_t*)(drow + 33792 + ((1 ^ sw) << 4)) = l;
      split8(f4, f5, h, m, l);
      *(short8_t*)(drow + ((2 ^ sw) << 4)) = h;
      *(short8_t*)(drow + 16896 + ((2 ^ sw) << 4)) = m;
      *(short8_t*)(drow + 33792 + ((2 ^ sw) << 4)) = l;
      split8(f6, f7, h, m, l);
      *(short8_t*)(drow + ((3 ^ sw) << 4)) = h;
      *(short8_t*)(drow + 16896 + ((3 ^ sw) << 4)) = m;
      *(short8_t*)(drow + 33792 + ((3 ^ sw) << 4)) = l;
    }
    for (int tap = 0; tap < 9; ++tap) {
      const int dy = tap / 3, dx = tap - dy * 3;
      __syncthreads();   // protect previous tap's Wl reads (and input writes for tap 0)
      // ---- stage weights: 128 ko x 32 c fp32 -> 3 bf16 planes ----
      for (int i = tid; i < 512; i += 256) {
        int ko_l = i >> 2, part = i & 3;
        const float4* wp = (const float4*)(Wt2 + (((size_t)tap * 512 + ko0 + ko_l) << 9) + c0 + part * 8);
        float4 wa = wp[0], wb = wp[1];
        short8_t h, m, l;
        split8(wa, wb, h, m, l);
        char* base = (char*)Wl + (ko_l << 6) + (((part ^ (ko_l & 3))) << 4);
        *(short8_t*)(base) = h;
        *(short8_t*)(base + 8192) = m;
        *(short8_t*)(base + 16384) = l;
      }
      __syncthreads();
      // ---- A fragments (weights) ----
      short8_t Ah[2], Am[2], Al[2];
      #pragma unroll
      for (int f = 0; f < 2; ++f) {
        int kol = (wave << 5) + (f << 4) + lm;
        char* ab = (char*)Wl + (kol << 6) + ((lg ^ (kol & 3)) << 4);
        Ah[f] = *(short8_t*)ab;
        Am[f] = *(short8_t*)(ab + 8192);
        Al[f] = *(short8_t*)(ab + 16384);
      }
      // ---- B fragments + MFMAs ----
      #pragma unroll
      for (int p = 0; p < 8; ++p) {
        const int yl = p >> 2;
        const int x  = ((p & 3) << 4) + lm;
        const int r  = yl + dy, xx = x + dx;
        char* bb = (char*)Slds + ((r * 66 + xx) << 6) + ((lg ^ (xx & 3)) << 4);
        short8_t Bh = *(short8_t*)bb;
        short8_t Bm = *(short8_t*)(bb + 16896);
        short8_t Bl = *(short8_t*)(bb + 33792);
        #pragma unroll
        for (int f = 0; f < 2; ++f) {
          acc[f][p] = __builtin_amdgcn_mfma_f32_16x16x32_bf16(Ah[f], Bh, acc[f][p], 0, 0, 0);
          acc[f][p] = __builtin_amdgcn_mfma_f32_16x16x32_bf16(Ah[f], Bm, acc[f][p], 0, 0, 0);
          acc[f][p] = __builtin_amdgcn_mfma_f32_16x16x32_bf16(Am[f], Bh, acc[f][p], 0, 0, 0);
          acc[f][p] = __builtin_amdgcn_mfma_f32_16x16x32_bf16(Ah[f], Bl, acc[f][p], 0, 0, 0);
          acc[f][p] = __builtin_amdgcn_mfma_f32_16x16x32_bf16(Al[f], Bh, acc[f][p], 0, 0, 0);
          acc[f][p] = __builtin_amdgcn_mfma_f32_16x16x32_bf16(Am[f], Bm, acc[f][p], 0, 0, 0);
        }
      }
    }
  }
  // ---- epilogue: bias + relu; C/D: col(pos)=lane&15, row(ko)=(lane>>4)*4+reg ----
  #pragma unroll
  for (int f = 0; f < 2; ++f) {
    const int koB = ko0 + (wave << 5) + (f << 4) + (lg << 2);
    #pragma unroll
    for (int reg = 0; reg < 4; ++reg) {
      const float bv = bias[koB + reg];
      #pragma unroll
      for (int p = 0; p < 8; ++p) {
        const int pos = pos0 + (p << 4) + lm;
        out[(((size_t)b * 512 + koB + reg) << 12) + pos] = fmaxf(acc[f][p][reg] + bv, 0.f);
      }
    }
  }
}

// ---------------- 1x1 heads: 6 groups of 9 outputs, 2 positions/thread ----------------
__global__ __launch_bounds__(256) void head9_k(
    const float* __restrict__ conv, const float* __restrict__ Wcls,
    const float* __restrict__ bcls, const float* __restrict__ Wbbox,
    const float* __restrict__ bbbox, float* __restrict__ head) {
  __shared__ float Wl[9][68];
  const int b = blockIdx.z;
  const int g = blockIdx.y;
  const int p0 = blockIdx.x * 512 + threadIdx.x;
  const int tid = threadIdx.x;
  float acc0[9] = {}, acc1[9] = {};
  const float* cb = conv + ((size_t)b * NC << 12);
  for (int c0 = 0; c0 < NC; c0 += 64) {
    __syncthreads();
    for (int e = tid; e < 9 * 64; e += 256) {
      int o = e >> 6; int c = e & 63;
      int go = g * 9 + o;
      Wl[o][c] = (go < 18) ? Wcls[go * 512 + c0 + c] : Wbbox[(go - 18) * 512 + c0 + c];
    }
    __syncthreads();
    #pragma unroll 4
    for (int c = 0; c < 64; c += 4) {
      float v00 = cb[((size_t)(c0 + c + 0) << 12) + p0];
      float v01 = cb[((size_t)(c0 + c + 1) << 12) + p0];
      float v02 = cb[((size_t)(c0 + c + 2) << 12) + p0];
      float v03 = cb[((size_t)(c0 + c + 3) << 12) + p0];
      float v10 = cb[((size_t)(c0 + c + 0) << 12) + p0 + 256];
      float v11 = cb[((size_t)(c0 + c + 1) << 12) + p0 + 256];
      float v12 = cb[((size_t)(c0 + c + 2) << 12) + p0 + 256];
      float v13 = cb[((size_t)(c0 + c + 3) << 12) + p0 + 256];
      #pragma unroll
      for (int o = 0; o < 9; ++o) {
        const float4 w = *(const float4*)&Wl[o][c];
        acc0[o] += w.x * v00; acc0[o] += w.y * v01; acc0[o] += w.z * v02; acc0[o] += w.w * v03;
        acc1[o] += w.x * v10; acc1[o] += w.y * v11; acc1[o] += w.z * v12; acc1[o] += w.w * v13;
      }
    }
  }
  #pragma unroll
  for (int o = 0; o < 9; ++o) {
    int go = g * 9 + o;
    float bv = (go < 18) ? bcls[go] : bbbox[go - 18];
    head[(((size_t)b * 54 + go) << 12) + p0]       = acc0[o] + bv;
    head[(((size_t)b * 54 + go) << 12) + p0 + 256] = acc1[o] + bv;
  }
}

// ---------------- score + box decode + clip + LDS histogram (pos-major) ----------------
__global__ __launch_bounds__(256) void decode_k(
    const float* __restrict__ head, const float* __restrict__ im_info,
    float* __restrict__ boxes, unsigned* __restrict__ skeys, unsigned* __restrict__ hist) {
  __shared__ unsigned hl[4096];
  const int tid = threadIdx.x;
  #pragma unroll
  for (int i = 0; i < 16; ++i) hl[tid + i * 256] = 0u;
  __syncthreads();
  const int p = blockIdx.x * 256 + tid;
  const int b = p >> 12; const int pos = p & 4095;
  const int x = pos & 63; const int y = pos >> 6;
  const float* hb = head + ((size_t)b * 54 << 12);
  const float imh = im_info[b * 3 + 0], imw = im_info[b * 3 + 1];
  float s[18];
  #pragma unroll
  for (int o = 0; o < 18; ++o) s[o] = hb[(o << 12) + pos];
  float d[36];
  #pragma unroll
  for (int o = 0; o < 36; ++o) d[o] = hb[((18 + o) << 12) + pos];
  const float sx = x * 16.f, sy = y * 16.f;
  #pragma unroll
  for (int a = 0; a < 9; ++a) {
    const float s0 = s[a], s1 = s[9 + a];
    const float m = fmaxf(s0, s1);
    const float e0 = expf(s0 - m), e1 = expf(s1 - m);
    const float score = e1 / (e0 + e1);
    const float d0 = d[a * 4 + 0], d1 = d[a * 4 + 1];
    const float d2 = d[a * 4 + 2], d3 = d[a * 4 + 3];
    const float ax1 = A9c[a][0] + sx, ay1 = A9c[a][1] + sy;
    const float ax2 = A9c[a][2] + sx, ay2 = A9c[a][3] + sy;
    const float aw = ax2 - ax1 + 1.f, ah = ay2 - ay1 + 1.f;
    const float acx = ax1 + 0.5f * aw, acy = ay1 + 0.5f * ah;
    const float pcx = d0 * aw + acx, pcy = d1 * ah + acy;
    const float pw = expf(d2) * aw, ph = expf(d3) * ah;
    const float x1 = fminf(fmaxf(pcx - 0.5f * pw, 0.f), imw - 1.f);
    const float y1 = fminf(fmaxf(pcy - 0.5f * ph, 0.f), imh - 1.f);
    const float x2 = fminf(fmaxf(pcx + 0.5f * pw, 0.f), imw - 1.f);
    const float y2 = fminf(fmaxf(pcy + 0.5f * ph, 0.f), imh - 1.f);
    const int n = pos * 9 + a;
    *(float4*)&boxes[((size_t)b * NANCH + n) * 4] = make_float4(x1, y1, x2, y2);
    const unsigned key = __float_as_uint(score);
    skeys[(size_t)b * NANCH + n] = key;
    atomicAdd(&hl[key >> 20], 1u);
  }
  __syncthreads();
  #pragma unroll
  for (int i = 0; i < 16; ++i) {
    unsigned c = hl[tid + i * 256];
    if (c) atomicAdd(&hist[b * 4096 + tid + i * 256], c);
  }
}

// ---------------- fused threshold select + compact (one block per batch) ----------------
__global__ __launch_bounds__(256) void select_k(
    const unsigned* __restrict__ skeys, const unsigned* __restrict__ hist,
    unsigned* __restrict__ misc, unsigned* __restrict__ ckey,
    unsigned* __restrict__ cidx) {
  const int b = blockIdx.x;
  const int tid = threadIdx.x;
  __shared__ unsigned csum[256];
  __shared__ unsigned hl2[256];
  __shared__ unsigned s_t1, s_cumAbove, s_T2, s_cnt;
  const unsigned* h = hist + b * 4096;
  unsigned s = 0;
  #pragma unroll
  for (int i = 0; i < 16; ++i) s += h[tid * 16 + i];
  csum[tid] = s;
  hl2[tid] = 0u;
  __syncthreads();
  if (tid == 0) {
    unsigned cum = 0; int chunk = 0;
    for (int c = 255; c >= 0; --c) {
      if (cum + csum[c] >= (unsigned)PRE_TOPN) { chunk = c; break; }
      cum += csum[c];
    }
    unsigned t1 = chunk * 16, cumAbove = cum;
    for (int i = 15; i >= 0; --i) {
      unsigned cnt = h[chunk * 16 + i];
      if (cum + cnt >= (unsigned)PRE_TOPN) { t1 = chunk * 16 + i; cumAbove = cum; break; }
      cum += cnt;
    }
    s_t1 = t1; s_cumAbove = cumAbove; s_cnt = 0u;
  }
  __syncthreads();
  const unsigned t1 = s_t1;
  const unsigned* sk = skeys + (size_t)b * NANCH;
  for (int t = tid; t < NANCH; t += 256) {
    unsigned key = sk[t];
    if ((key >> 20) == t1) atomicAdd(&hl2[(key >> 12) & 255u], 1u);
  }
  __syncthreads();
  if (tid == 0) {
    unsigned cum = s_cumAbove;
    unsigned T2 = t1 << 20;
    for (int ss = 255; ss >= 0; --ss) {
      unsigned c = hl2[ss];
      if (cum + c >= (unsigned)PRE_TOPN) { T2 = (t1 << 20) | ((unsigned)ss << 12); break; }
      cum += c;
    }
    s_T2 = T2;
  }
  __syncthreads();
  const unsigned T2 = s_T2;
  const int lane = tid & 63;
  for (int t = tid; t < NANCH; t += 256) {
    unsigned key = sk[t];
    bool pred = key >= T2;
    unsigned long long mb = __ballot(pred);
    unsigned base = 0;
    if (lane == 0) base = atomicAdd(&s_cnt, (unsigned)__popcll(mb));
    base = (unsigned)__shfl((int)base, 0, 64);
    if (pred) {
      unsigned pp = base + (unsigned)__popcll(mb & ((1ull << lane) - 1ull));
      if (pp < (unsigned)CAND_CAP) {
        ckey[(size_t)b * CAND_CAP + pp] = key;
        cidx[(size_t)b * CAND_CAP + pp] = (unsigned)t;
      }
    }
  }
  __syncthreads();
  if (tid == 0) misc[12 + b] = s_cnt;
}

// ---------------- exact rank sort of candidates (desc score, asc index) ----------------
__global__ __launch_bounds__(256) void rank_scatter_k(
    const unsigned* __restrict__ ckey, const unsigned* __restrict__ cidx,
    const unsigned* __restrict__ misc, const float* __restrict__ boxes,
    float* __restrict__ sbox) {
  const int b = blockIdx.y;
  const int K = min((int)misc[12 + b], CAND_CAP);
  const int i = blockIdx.x * 256 + threadIdx.x;
  unsigned mykey = 0, myidx = 0;
  const bool active = i < K;
  if (active) {
    mykey = ckey[(size_t)b * CAND_CAP + i];
    myidx = cidx[(size_t)b * CAND_CAP + i];
  }
  int rank = 0;
  __shared__ unsigned skey[1024];
  __shared__ unsigned sidx[1024];
  for (int c0 = 0; c0 < K; c0 += 1024) {
    int n = min(1024, K - c0);
    __syncthreads();
    for (int e = threadIdx.x; e < n; e += 256) {
      skey[e] = ckey[(size_t)b * CAND_CAP + c0 + e];
      sidx[e] = cidx[(size_t)b * CAND_CAP + c0 + e];
    }
    __syncthreads();
    if (active) {
      for (int j = 0; j < n; ++j) {
        unsigned kj = skey[j];
        rank += (kj > mykey) || (kj == mykey && sidx[j] < myidx);
      }
    }
  }
  if (active && rank < PRE_TOPN) {
    float4 bx = *(const float4*)&boxes[((size_t)b * NANCH + myidx) * 4];
    *(float4*)&sbox[((size_t)b * PRE_TOPN + rank) * 4] = bx;
  }
}

// ---------------- IoU suppression bit-matrix ----------------
__global__ __launch_bounds__(256) void iou_mask_k(const float* __restrict__ sbox,
                                                  unsigned long long* __restrict__ mask) {
  __shared__ float4 jb[3008];
  __shared__ float4 ib[32];
  const int b  = blockIdx.z;
  const int i0 = blockIdx.y * 32;
  const int w0 = blockIdx.x * 47;
  const int j0 = w0 * 64;
  const int nj = min(3008, PRE_TOPN - j0);
  const int tid = threadIdx.x;
  const float4* S = (const float4*)(sbox + (size_t)b * PRE_TOPN * 4);
  for (int e = tid; e < nj; e += 256) jb[e] = S[j0 + e];
  if (tid < 32 && i0 + tid < PRE_TOPN) ib[tid] = S[i0 + tid];
  __syncthreads();
  for (int idx = tid; idx < 32 * 47; idx += 256) {
    const int il = idx / 47, wl = idx - il * 47;
    const int i = i0 + il;
    if (i >= PRE_TOPN) continue;
    const float4 p = ib[il];
    const float parea = (p.z - p.x + 1.f) * (p.w - p.y + 1.f);
    unsigned long long m = 0;
    const int jb0 = wl * 64;
    #pragma unroll 8
    for (int q = 0; q < 64; ++q) {
      const int j = jb0 + q;
      const float4 qb = jb[j];
      float xx1 = fmaxf(p.x, qb.x), yy1 = fmaxf(p.y, qb.y);
      float xx2 = fminf(p.z, qb.z), yy2 = fminf(p.w, qb.w);
      float inter = fmaxf(xx2 - xx1 + 1.f, 0.f) * fmaxf(yy2 - yy1 + 1.f, 0.f);
      float area = (qb.z - qb.x + 1.f) * (qb.w - qb.y + 1.f);
      float iou = inter / (parea + area - inter);
      if (iou > 0.7f && j < nj) m |= (1ull << q);
    }
    mask[((size_t)b * PRE_TOPN + i) * MROW + w0 + wl] = m;
  }
}

// ---------------- wave-synchronous greedy pick ----------------
__device__ inline unsigned long long shfl_u64(unsigned long long v, int src) {
  int lo = __shfl((int)(unsigned)v, src, 64);
  int hi = __shfl((int)(unsigned)(v >> 32), src, 64);
  return ((unsigned long long)(unsigned)hi << 32) | (unsigned)lo;
}

__global__ __launch_bounds__(64) void nms_pick_k(const float* __restrict__ sbox,
                                                 const unsigned long long* __restrict__ mask,
                                                 float* __restrict__ out) {
  const int b = blockIdx.x;
  const int lane = threadIdx.x;
  unsigned long long va = ~0ull;
  unsigned long long vb = (lane < 29) ? ~0ull : (lane == 29 ? ((1ull << 48) - 1ull) : 0ull);
  const float* Bb = sbox + (size_t)b * PRE_TOPN * 4;
  float* O = out + (size_t)b * POST_TOPN * 5;
  int done = POST_TOPN;
  for (int it = 0; it < POST_TOPN; ++it) {
    unsigned long long ba = __ballot(va != 0ull);
    unsigned long long bb = __ballot(vb != 0ull);
    int w; unsigned long long word;
    if (ba) {
      w = __ffsll((long long)ba) - 1;
      word = shfl_u64(va, w);
    } else if (bb) {
      w = __ffsll((long long)bb) - 1;
      word = shfl_u64(vb, w);
      w += 64;
    } else { done = it; break; }
    const int i = (w << 6) + __ffsll((long long)word) - 1;
    const unsigned long long* row = mask + ((size_t)b * PRE_TOPN + i) * MROW;
    unsigned long long ra = row[lane];
    unsigned long long rb = (lane < 30) ? row[64 + lane] : 0ull;
    if (lane < 4) O[it * 5 + 1 + lane] = Bb[(size_t)i * 4 + lane];
    if (lane == 4) O[it * 5] = (float)b;
    va &= ~ra;
    vb &= ~rb;
  }
  for (int e = lane; e < (POST_TOPN - done) * 5; e += 64) {
    int r = done + e / 5; int c = e - (e / 5) * 5;
    O[r * 5 + c] = (c == 0) ? (float)b : 0.f;
  }
}

// ---------------- launch ----------------
extern "C" void kernel_launch(void* const* d_in, const int* in_sizes, int n_in,
                              void* d_out, int out_size, void* d_ws, size_t ws_size,
                              hipStream_t stream) {
  const float* base_feat = (const float*)d_in[0];
  const float* im_info   = (const float*)d_in[1];
  const float* W_conv    = (const float*)d_in[4];
  const float* b_conv    = (const float*)d_in[5];
  const float* W_cls     = (const float*)d_in[6];
  const float* b_cls     = (const float*)d_in[7];
  const float* W_bbox    = (const float*)d_in[8];
  const float* b_bbox    = (const float*)d_in[9];
  float* out = (float*)d_out;
  char* ws = (char*)d_ws;

  float*    Wt2   = (float*)(ws + OFF_WT2);
  float*    It    = (float*)(ws + OFF_IT);
  float*    conv  = (float*)(ws + OFF_CONV);
  unsigned long long* mask = (unsigned long long*)(ws + OFF_MASK);  // overlays It (dead after conv)
  float*    head  = (float*)(ws + OFF_HEAD);                        // overlays Wt2 (dead after conv)
  unsigned* skeys = (unsigned*)(ws + OFF_SKEY);
  float*    boxes = (float*)(ws + OFF_BOX);
  unsigned* hist  = (unsigned*)(ws + OFF_HIST);
  unsigned* misc  = (unsigned*)(ws + OFF_MISC);
  unsigned* ckey  = (unsigned*)(ws + OFF_CKEY);
  unsigned* cidx  = (unsigned*)(ws + OFF_CIDX);
  float*    sbox  = (float*)(ws + OFF_SBOX);

  hipMemsetAsync(ws + OFF_HIST, 0, 65536 + 256, stream);

  wtrans2_k<<<9216, 256, 0, stream>>>(W_conv, Wt2);
  cvtI_k<<<dim3(64, 8, 4), 256, 0, stream>>>(base_feat, It);
  conv_mfma_k<<<dim3(32, 4, 4), 256, 0, stream>>>(It, Wt2, b_conv, conv);
  head9_k<<<dim3(8, 6, 4), 256, 0, stream>>>(conv, W_cls, b_cls, W_bbox, b_bbox, head);
  decode_k<<<64, 256, 0, stream>>>(head, im_info, boxes, skeys, hist);
  select_k<<<4, 256, 0, stream>>>(skeys, hist, misc, ckey, cidx);
  rank_scatter_k<<<dim3(CAND_CAP / 256, 4), 256, 0, stream>>>(ckey, cidx, misc, boxes, sbox);
  iou_mask_k<<<dim3(2, 188, 4), 256, 0, stream>>>(sbox, mask);
  nms_pick_k<<<4, 64, 0, stream>>>(sbox, mask, out);
}

// Round 10
// 1076.103 us; speedup vs baseline: 2.1004x; 1.1046x over previous
//
#include <hip/hip_runtime.h>
#include <math.h>

// ---------------- problem constants ----------------
constexpr int NB = 4;            // batch
constexpr int NC = 512;          // channels
constexpr int NH = 64, NW = 64;  // spatial
constexpr int NPOS = NH * NW;        // 4096
constexpr int NANCH = NPOS * 9;      // 36864 anchors/batch
constexpr int PRE_TOPN = 6000;
constexpr int POST_TOPN = 300;
constexpr int CAND_CAP = 40960;
constexpr int MROW = 96;             // mask row stride in u64 (94 used)

typedef short short8_t __attribute__((ext_vector_type(8)));
typedef float f32x4_t __attribute__((ext_vector_type(4)));

// anchors for base_size=16, ratios {0.5,1,2}, scales {8,16,32} (verified vs numpy)
__device__ __constant__ float A9c[9][4] = {
  {-84.f,-40.f,99.f,55.f},   {-176.f,-88.f,191.f,103.f}, {-360.f,-184.f,375.f,199.f},
  {-56.f,-56.f,71.f,71.f},   {-120.f,-120.f,135.f,135.f},{-248.f,-248.f,263.f,263.f},
  {-36.f,-80.f,51.f,95.f},   {-80.f,-168.f,95.f,183.f},  {-168.f,-344.f,183.f,359.f}};

// ---------------- ws layout (bytes) ----------------
constexpr size_t OFF_WT2  = 0;          // 9*512*512*4  = 9,437,184 (fp32 W [tap][ko][c]; dead after conv)
constexpr size_t OFF_IT   = 9437184;    // 4*4096*512*4 = 33,554,432 (fp32 input [b][pos][c]; dead after conv)
constexpr size_t OFF_CONV = 42991616;   // 4*512*4096*4 = 33,554,432
constexpr size_t OFF_HIST = 76546048;   // 4*4096*4 = 65,536
constexpr size_t OFF_MISC = 76611584;   // 256
// overlays (written only after their host region is dead):
constexpr size_t OFF_MASK = OFF_IT;     // 4*6000*96*8 = 18,432,000 <= 33.5 MB (after conv)
constexpr size_t OFF_HEAD = 0;          // 3,538,944  (after conv, inside WT2)
constexpr size_t OFF_SKEY = 3538944;    // 589,824
constexpr size_t OFF_BOX  = 4128768;    // 2,359,296
constexpr size_t OFF_CKEY = 6488064;    // 655,360
constexpr size_t OFF_CIDX = 7143424;    // 655,360
constexpr size_t OFF_SBOX = 7798784;    // 384,000 -> end 8,182,784 < 9,437,184 OK
// total ws = 76,611,840 bytes

// ---------------- bf16 helpers (RNE) ----------------
__device__ inline unsigned short f2bf(float f) {
  unsigned u = __float_as_uint(f);
  unsigned r = u + 0x7fffu + ((u >> 16) & 1u);
  return (unsigned short)(r >> 16);
}
__device__ inline float bf2f(unsigned short h) { return __uint_as_float(((unsigned)h) << 16); }

// split 8 floats into hi/mid/lo bf16 (24 mantissa bits total)
__device__ inline void split8(const float4 A, const float4 B, short8_t& h, short8_t& m, short8_t& l) {
#define SPL(J, X) { unsigned short hh = f2bf(X); float fh = bf2f(hh); \
                    unsigned short mm = f2bf((X) - fh); float fm = bf2f(mm); \
                    unsigned short ll = f2bf((X) - fh - fm); \
                    h[J] = (short)hh; m[J] = (short)mm; l[J] = (short)ll; }
  SPL(0, A.x) SPL(1, A.y) SPL(2, A.z) SPL(3, A.w)
  SPL(4, B.x) SPL(5, B.y) SPL(6, B.z) SPL(7, B.w)
#undef SPL
}

// ---------------- W[ko][c][tap] -> Wt2[tap][ko][c] (fp32) ----------------
__global__ __launch_bounds__(256) void wtrans2_k(const float* __restrict__ Wc,
                                                float* __restrict__ Wt2) {
  int i = blockIdx.x * 256 + threadIdx.x;   // exact: 9*512*512 / 256 = 9216 blocks
  int tap = i >> 18;
  int rem = i & 262143;
  int ko = rem >> 9, c = rem & 511;
  Wt2[i] = Wc[(size_t)ko * 4608 + c * 9 + tap];
}

// ---------------- input [b][c][pos] -> It [b][pos][c] (fp32 transpose) ----------------
__global__ __launch_bounds__(256) void cvtI_k(const float* __restrict__ in,
                                              float* __restrict__ It) {
  __shared__ float T[64][65];
  const int b = blockIdx.z, c0 = blockIdx.y * 64, pos0 = blockIdx.x * 64;
  const int tid = threadIdx.x;
  for (int i = tid; i < 4096; i += 256) {
    int cc = i >> 6, pp = i & 63;
    T[cc][pp] = in[(((size_t)b * 512 + c0 + cc) << 12) + pos0 + pp];
  }
  __syncthreads();
  for (int i = tid; i < 4096; i += 256) {
    int pp = i >> 6, cc = i & 63;
    It[((((size_t)b << 12) + pos0 + pp) << 9) + c0 + cc] = T[cc][pp];
  }
}

// ---------------- conv3x3 + bias + relu via MFMA (bf16x3 split, 6 products) ----------------
// Block: 128 ko x 128 pos (2 y-rows), 4 waves; wave owns 2 ko-frags x 8 pos-frags.
// LDS swizzle g(row) = (row>>1)&3: 8 consecutive rows cover all 8 bank-quads -> only
// the free 2-way aliasing remains (fix for R9's 3.9e7 conflicts from g(row)=row&3).
__global__ __launch_bounds__(256, 2) void conv_mfma_k(
    const float* __restrict__ It, const float* __restrict__ Wt2,
    const float* __restrict__ bias, float* __restrict__ out) {
  __shared__ short Slds[3 * 264 * 32];   // [plane][r*66+xx][32c] 50,688 B
  __shared__ short Wl[3 * 128 * 32];     // [plane][ko][32c]     24,576 B
  const int tid = threadIdx.x;
  const int wave = tid >> 6, lane = tid & 63;
  const int lm = lane & 15, lg = lane >> 4;
  const int pos0 = blockIdx.x * 128;
  const int ko0  = blockIdx.y * 128;
  const int b    = blockIdx.z;
  const int y0   = pos0 >> 6;            // first of 2 output rows

  f32x4_t acc[2][8];
  #pragma unroll
  for (int f = 0; f < 2; ++f)
    #pragma unroll
    for (int p = 0; p < 8; ++p) acc[f][p] = (f32x4_t){0.f, 0.f, 0.f, 0.f};

  for (int c0 = 0; c0 < 512; c0 += 32) {
    __syncthreads();   // protect previous tap's Slds reads
    // ---- stage input: 264 slots (4 rows x 66 xx) x 32 c, fp32 -> 3 bf16 planes ----
    for (int i = tid; i < 264; i += 256) {
      int r = i / 66, xx = i - r * 66;
      int gy = y0 + r - 1, gx = xx - 1;
      bool ok = ((unsigned)gy < 64u) && ((unsigned)gx < 64u);
      float4 f0 = {}, f1 = {}, f2 = {}, f3 = {}, f4 = {}, f5 = {}, f6 = {}, f7 = {};
      if (ok) {
        const float4* gp = (const float4*)(It + ((((size_t)b << 12) + (gy << 6) + gx) << 9) + c0);
        f0 = gp[0]; f1 = gp[1]; f2 = gp[2]; f3 = gp[3];
        f4 = gp[4]; f5 = gp[5]; f6 = gp[6]; f7 = gp[7];
      }
      const int sw = (xx >> 1) & 3;
      char* drow = (char*)Slds + (i << 6);
      short8_t h, m, l;
      split8(f0, f1, h, m, l);
      *(short8_t*)(drow + ((0 ^ sw) << 4)) = h;
      *(short8_t*)(drow + 16896 + ((0 ^ sw) << 4)) = m;
      *(short8_t*)(drow + 33792 + ((0 ^ sw) << 4)) = l;
      split8(f2, f3, h, m, l);
      *(short8_t*)(drow + ((1 ^ sw) << 4)) = h;
      *(short8_t*)(drow + 16896 + ((1 ^ sw) << 4)) = m;
      *(short8_t*)(drow + 33792 + ((1 ^ sw) << 4)) = l;
      split8(f4, f5, h, m, l);
      *(short8_t*)(drow + ((2 ^ sw) << 4)) = h;
      *(short8_t*)(drow + 16896 + ((2 ^ sw) << 4)) = m;
      *(short8_t*)(drow + 33792 + ((2 ^ sw) << 4)) = l;
      split8(f6, f7, h, m, l);
      *(short8_t*)(drow + ((3 ^ sw) << 4)) = h;
      *(short8_t*)(drow + 16896 + ((3 ^ sw) << 4)) = m;
      *(short8_t*)(drow + 33792 + ((3 ^ sw) << 4)) = l;
    }
    for (int tap = 0; tap < 9; ++tap) {
      const int dy = tap / 3, dx = tap - dy * 3;
      __syncthreads();   // protect previous tap's Wl reads (and input writes for tap 0)
      // ---- stage weights: 128 ko x 32 c fp32 -> 3 bf16 planes ----
      for (int i = tid; i < 512; i += 256) {
        int ko_l = i >> 2, part = i & 3;
        const float4* wp = (const float4*)(Wt2 + (((size_t)tap * 512 + ko0 + ko_l) << 9) + c0 + part * 8);
        float4 wa = wp[0], wb = wp[1];
        short8_t h, m, l;
        split8(wa, wb, h, m, l);
        char* base = (char*)Wl + (ko_l << 6) + ((part ^ ((ko_l >> 1) & 3)) << 4);
        *(short8_t*)(base) = h;
        *(short8_t*)(base + 8192) = m;
        *(short8_t*)(base + 16384) = l;
      }
      __syncthreads();
      // ---- A fragments (weights) ----
      short8_t Ah[2], Am[2], Al[2];
      #pragma unroll
      for (int f = 0; f < 2; ++f) {
        int kol = (wave << 5) + (f << 4) + lm;
        char* ab = (char*)Wl + (kol << 6) + ((lg ^ ((kol >> 1) & 3)) << 4);
        Ah[f] = *(short8_t*)ab;
        Am[f] = *(short8_t*)(ab + 8192);
        Al[f] = *(short8_t*)(ab + 16384);
      }
      // ---- B fragments + MFMAs ----
      #pragma unroll
      for (int p = 0; p < 8; ++p) {
        const int yl = p >> 2;
        const int x  = ((p & 3) << 4) + lm;
        const int r  = yl + dy, xx = x + dx;
        char* bb = (char*)Slds + ((r * 66 + xx) << 6) + ((lg ^ ((xx >> 1) & 3)) << 4);
        short8_t Bh = *(short8_t*)bb;
        short8_t Bm = *(short8_t*)(bb + 16896);
        short8_t Bl = *(short8_t*)(bb + 33792);
        #pragma unroll
        for (int f = 0; f < 2; ++f) {
          acc[f][p] = __builtin_amdgcn_mfma_f32_16x16x32_bf16(Ah[f], Bh, acc[f][p], 0, 0, 0);
          acc[f][p] = __builtin_amdgcn_mfma_f32_16x16x32_bf16(Ah[f], Bm, acc[f][p], 0, 0, 0);
          acc[f][p] = __builtin_amdgcn_mfma_f32_16x16x32_bf16(Am[f], Bh, acc[f][p], 0, 0, 0);
          acc[f][p] = __builtin_amdgcn_mfma_f32_16x16x32_bf16(Ah[f], Bl, acc[f][p], 0, 0, 0);
          acc[f][p] = __builtin_amdgcn_mfma_f32_16x16x32_bf16(Al[f], Bh, acc[f][p], 0, 0, 0);
          acc[f][p] = __builtin_amdgcn_mfma_f32_16x16x32_bf16(Am[f], Bm, acc[f][p], 0, 0, 0);
        }
      }
    }
  }
  // ---- epilogue: bias + relu; C/D: col(pos)=lane&15, row(ko)=(lane>>4)*4+reg ----
  #pragma unroll
  for (int f = 0; f < 2; ++f) {
    const int koB = ko0 + (wave << 5) + (f << 4) + (lg << 2);
    #pragma unroll
    for (int reg = 0; reg < 4; ++reg) {
      const float bv = bias[koB + reg];
      #pragma unroll
      for (int p = 0; p < 8; ++p) {
        const int pos = pos0 + (p << 4) + lm;
        out[(((size_t)b * 512 + koB + reg) << 12) + pos] = fmaxf(acc[f][p][reg] + bv, 0.f);
      }
    }
  }
}

// ---------------- 1x1 heads via MFMA: 54 (pad 64) x 512 x 4096/batch ----------------
// Block: 64 ko x 128 pos, 4 waves; wave owns all 4 ko-frags x 2 pos-frags.
// B staged directly from conv [c][pos] (coalesced: lanes = consecutive pos).
__global__ __launch_bounds__(256, 4) void head_mfma_k(
    const float* __restrict__ conv, const float* __restrict__ Wcls,
    const float* __restrict__ bcls, const float* __restrict__ Wbbox,
    const float* __restrict__ bbbox, float* __restrict__ head) {
  __shared__ short Bl[3 * 128 * 32];   // [plane][pos][32c] 24,576 B
  __shared__ short Al[3 * 64 * 32];    // [plane][ko][32c]  12,288 B
  const int tid = threadIdx.x;
  const int wave = tid >> 6, lane = tid & 63;
  const int lm = lane & 15, lg = lane >> 4;
  const int pos0 = blockIdx.x * 128;
  const int b    = blockIdx.y;

  f32x4_t acc[4][2];
  #pragma unroll
  for (int f = 0; f < 4; ++f)
    #pragma unroll
    for (int pi = 0; pi < 2; ++pi) acc[f][pi] = (f32x4_t){0.f, 0.f, 0.f, 0.f};

  const float* cb = conv + ((size_t)b * 512 << 12);

  for (int c0 = 0; c0 < 512; c0 += 32) {
    __syncthreads();
    // ---- stage B: 128 pos x 32 c (2 tasks/thread), coalesced global reads ----
    for (int task = tid; task < 512; task += 256) {
      const int pos_l = task & 127, ch = task >> 7;
      float v[8];
      #pragma unroll
      for (int j = 0; j < 8; ++j)
        v[j] = cb[((size_t)(c0 + ch * 8 + j) << 12) + pos0 + pos_l];
      short8_t h, m, l;
      split8(make_float4(v[0], v[1], v[2], v[3]), make_float4(v[4], v[5], v[6], v[7]), h, m, l);
      char* base = (char*)Bl + (pos_l << 6) + ((ch ^ ((pos_l >> 1) & 3)) << 4);
      *(short8_t*)(base) = h;
      *(short8_t*)(base + 8192) = m;
      *(short8_t*)(base + 16384) = l;
    }
    // ---- stage A: 64 ko x 32 c (rows >= 54 zero) ----
    {
      const int ko = tid >> 2, part = tid & 3;
      float4 wa = {}, wb = {};
      if (ko < 54) {
        const float* src = (ko < 18) ? (Wcls + (size_t)ko * 512) : (Wbbox + (size_t)(ko - 18) * 512);
        wa = *(const float4*)(src + c0 + part * 8);
        wb = *(const float4*)(src + c0 + part * 8 + 4);
      }
      short8_t h, m, l;
      split8(wa, wb, h, m, l);
      char* base = (char*)Al + (ko << 6) + ((part ^ ((ko >> 1) & 3)) << 4);
      *(short8_t*)(base) = h;
      *(short8_t*)(base + 4096) = m;
      *(short8_t*)(base + 8192) = l;
    }
    __syncthreads();
    // ---- fragments + MFMAs ----
    short8_t Ah[4], Am[4], Av[4];
    #pragma unroll
    for (int f = 0; f < 4; ++f) {
      const int kol = (f << 4) + lm;
      char* ab = (char*)Al + (kol << 6) + ((lg ^ ((kol >> 1) & 3)) << 4);
      Ah[f] = *(short8_t*)ab;
      Am[f] = *(short8_t*)(ab + 4096);
      Av[f] = *(short8_t*)(ab + 8192);
    }
    #pragma unroll
    for (int pi = 0; pi < 2; ++pi) {
      const int pos_l = ((wave << 1) + pi) * 16 + lm;
      char* bb = (char*)Bl + (pos_l << 6) + ((lg ^ ((pos_l >> 1) & 3)) << 4);
      short8_t Bh = *(short8_t*)bb;
      short8_t Bm = *(short8_t*)(bb + 8192);
      short8_t Bv = *(short8_t*)(bb + 16384);
      #pragma unroll
      for (int f = 0; f < 4; ++f) {
        acc[f][pi] = __builtin_amdgcn_mfma_f32_16x16x32_bf16(Ah[f], Bh, acc[f][pi], 0, 0, 0);
        acc[f][pi] = __builtin_amdgcn_mfma_f32_16x16x32_bf16(Ah[f], Bm, acc[f][pi], 0, 0, 0);
        acc[f][pi] = __builtin_amdgcn_mfma_f32_16x16x32_bf16(Am[f], Bh, acc[f][pi], 0, 0, 0);
        acc[f][pi] = __builtin_amdgcn_mfma_f32_16x16x32_bf16(Ah[f], Bv, acc[f][pi], 0, 0, 0);
        acc[f][pi] = __builtin_amdgcn_mfma_f32_16x16x32_bf16(Av[f], Bh, acc[f][pi], 0, 0, 0);
        acc[f][pi] = __builtin_amdgcn_mfma_f32_16x16x32_bf16(Am[f], Bm, acc[f][pi], 0, 0, 0);
      }
    }
  }
  // ---- epilogue: bias (no relu); col(pos)=lm, row(ko)=lg*4+reg within frag ----
  #pragma unroll
  for (int f = 0; f < 4; ++f) {
    #pragma unroll
    for (int reg = 0; reg < 4; ++reg) {
      const int ko = (f << 4) + (lg << 2) + reg;
      if (ko < 54) {
        const float bv = (ko < 18) ? bcls[ko] : bbbox[ko - 18];
        #pragma unroll
        for (int pi = 0; pi < 2; ++pi) {
          const int pos = pos0 + ((wave << 1) + pi) * 16 + lm;
          head[(((size_t)b * 54 + ko) << 12) + pos] = acc[f][pi][reg] + bv;
        }
      }
    }
  }
}

// ---------------- score + box decode + clip + LDS histogram (pos-major) ----------------
__global__ __launch_bounds__(256) void decode_k(
    const float* __restrict__ head, const float* __restrict__ im_info,
    float* __restrict__ boxes, unsigned* __restrict__ skeys, unsigned* __restrict__ hist) {
  __shared__ unsigned hl[4096];
  const int tid = threadIdx.x;
  #pragma unroll
  for (int i = 0; i < 16; ++i) hl[tid + i * 256] = 0u;
  __syncthreads();
  const int p = blockIdx.x * 256 + tid;
  const int b = p >> 12; const int pos = p & 4095;
  const int x = pos & 63; const int y = pos >> 6;
  const float* hb = head + ((size_t)b * 54 << 12);
  const float imh = im_info[b * 3 + 0], imw = im_info[b * 3 + 1];
  float s[18];
  #pragma unroll
  for (int o = 0; o < 18; ++o) s[o] = hb[(o << 12) + pos];
  float d[36];
  #pragma unroll
  for (int o = 0; o < 36; ++o) d[o] = hb[((18 + o) << 12) + pos];
  const float sx = x * 16.f, sy = y * 16.f;
  #pragma unroll
  for (int a = 0; a < 9; ++a) {
    const float s0 = s[a], s1 = s[9 + a];
    const float m = fmaxf(s0, s1);
    const float e0 = expf(s0 - m), e1 = expf(s1 - m);
    const float score = e1 / (e0 + e1);
    const float d0 = d[a * 4 + 0], d1 = d[a * 4 + 1];
    const float d2 = d[a * 4 + 2], d3 = d[a * 4 + 3];
    const float ax1 = A9c[a][0] + sx, ay1 = A9c[a][1] + sy;
    const float ax2 = A9c[a][2] + sx, ay2 = A9c[a][3] + sy;
    const float aw = ax2 - ax1 + 1.f, ah = ay2 - ay1 + 1.f;
    const float acx = ax1 + 0.5f * aw, acy = ay1 + 0.5f * ah;
    const float pcx = d0 * aw + acx, pcy = d1 * ah + acy;
    const float pw = expf(d2) * aw, ph = expf(d3) * ah;
    const float x1 = fminf(fmaxf(pcx - 0.5f * pw, 0.f), imw - 1.f);
    const float y1 = fminf(fmaxf(pcy - 0.5f * ph, 0.f), imh - 1.f);
    const float x2 = fminf(fmaxf(pcx + 0.5f * pw, 0.f), imw - 1.f);
    const float y2 = fminf(fmaxf(pcy + 0.5f * ph, 0.f), imh - 1.f);
    const int n = pos * 9 + a;
    *(float4*)&boxes[((size_t)b * NANCH + n) * 4] = make_float4(x1, y1, x2, y2);
    const unsigned key = __float_as_uint(score);
    skeys[(size_t)b * NANCH + n] = key;
    atomicAdd(&hl[key >> 20], 1u);
  }
  __syncthreads();
  #pragma unroll
  for (int i = 0; i < 16; ++i) {
    unsigned c = hl[tid + i * 256];
    if (c) atomicAdd(&hist[b * 4096 + tid + i * 256], c);
  }
}

// ---------------- fused threshold select + compact (one block per batch, 512 thr) ------
__global__ __launch_bounds__(512) void select_k(
    const unsigned* __restrict__ skeys, const unsigned* __restrict__ hist,
    unsigned* __restrict__ misc, unsigned* __restrict__ ckey,
    unsigned* __restrict__ cidx) {
  const int b = blockIdx.x;
  const int tid = threadIdx.x;
  __shared__ unsigned csum[256];
  __shared__ unsigned hl2[256];
  __shared__ unsigned s_t1, s_cumAbove, s_T2, s_cnt;
  const unsigned* h = hist + b * 4096;
  if (tid < 256) {
    unsigned s = 0;
    #pragma unroll
    for (int i = 0; i < 16; ++i) s += h[tid * 16 + i];
    csum[tid] = s;
    hl2[tid] = 0u;
  }
  __syncthreads();
  if (tid == 0) {
    unsigned cum = 0; int chunk = 0;
    for (int c = 255; c >= 0; --c) {
      if (cum + csum[c] >= (unsigned)PRE_TOPN) { chunk = c; break; }
      cum += csum[c];
    }
    unsigned t1 = chunk * 16, cumAbove = cum;
    for (int i = 15; i >= 0; --i) {
      unsigned cnt = h[chunk * 16 + i];
      if (cum + cnt >= (unsigned)PRE_TOPN) { t1 = chunk * 16 + i; cumAbove = cum; break; }
      cum += cnt;
    }
    s_t1 = t1; s_cumAbove = cumAbove; s_cnt = 0u;
  }
  __syncthreads();
  const unsigned t1 = s_t1;
  const unsigned* sk = skeys + (size_t)b * NANCH;
  for (int t = tid; t < NANCH; t += 512) {
    unsigned key = sk[t];
    if ((key >> 20) == t1) atomicAdd(&hl2[(key >> 12) & 255u], 1u);
  }
  __syncthreads();
  if (tid == 0) {
    unsigned cum = s_cumAbove;
    unsigned T2 = t1 << 20;
    for (int ss = 255; ss >= 0; --ss) {
      unsigned c = hl2[ss];
      if (cum + c >= (unsigned)PRE_TOPN) { T2 = (t1 << 20) | ((unsigned)ss << 12); break; }
      cum += c;
    }
    s_T2 = T2;
  }
  __syncthreads();
  const unsigned T2 = s_T2;
  const int lane = tid & 63;
  for (int t = tid; t < NANCH; t += 512) {   // NANCH % 512 == 0: uniform trip count
    unsigned key = sk[t];
    bool pred = key >= T2;
    unsigned long long mb = __ballot(pred);
    unsigned base = 0;
    if (lane == 0) base = atomicAdd(&s_cnt, (unsigned)__popcll(mb));
    base = (unsigned)__shfl((int)base, 0, 64);
    if (pred) {
      unsigned pp = base + (unsigned)__popcll(mb & ((1ull << lane) - 1ull));
      if (pp < (unsigned)CAND_CAP) {
        ckey[(size_t)b * CAND_CAP + pp] = key;
        cidx[(size_t)b * CAND_CAP + pp] = (unsigned)t;
      }
    }
  }
  __syncthreads();
  if (tid == 0) misc[12 + b] = s_cnt;
}

// ---------------- exact rank sort of candidates (desc score, asc index) ----------------
__global__ __launch_bounds__(256) void rank_scatter_k(
    const unsigned* __restrict__ ckey, const unsigned* __restrict__ cidx,
    const unsigned* __restrict__ misc, const float* __restrict__ boxes,
    float* __restrict__ sbox) {
  const int b = blockIdx.y;
  const int K = min((int)misc[12 + b], CAND_CAP);
  const int i = blockIdx.x * 256 + threadIdx.x;
  unsigned mykey = 0, myidx = 0;
  const bool active = i < K;
  if (active) {
    mykey = ckey[(size_t)b * CAND_CAP + i];
    myidx = cidx[(size_t)b * CAND_CAP + i];
  }
  int rank = 0;
  __shared__ unsigned skey[1024];
  __shared__ unsigned sidx[1024];
  for (int c0 = 0; c0 < K; c0 += 1024) {
    int n = min(1024, K - c0);
    __syncthreads();
    for (int e = threadIdx.x; e < n; e += 256) {
      skey[e] = ckey[(size_t)b * CAND_CAP + c0 + e];
      sidx[e] = cidx[(size_t)b * CAND_CAP + c0 + e];
    }
    __syncthreads();
    if (active) {
      for (int j = 0; j < n; ++j) {
        unsigned kj = skey[j];
        rank += (kj > mykey) || (kj == mykey && sidx[j] < myidx);
      }
    }
  }
  if (active && rank < PRE_TOPN) {
    float4 bx = *(const float4*)&boxes[((size_t)b * NANCH + myidx) * 4];
    *(float4*)&sbox[((size_t)b * PRE_TOPN + rank) * 4] = bx;
  }
}

// ---------------- IoU suppression bit-matrix (upper-triangle only) ----------------
// Picks strictly ascend in nms_pick, so words whose whole j-range lies below the
// i-tile are never consulted (valid bits there already 0) — garbage-safe to skip.
__global__ __launch_bounds__(256) void iou_mask_k(const float* __restrict__ sbox,
                                                  unsigned long long* __restrict__ mask) {
  __shared__ float4 jb[3008];
  __shared__ float4 ib[32];
  const int b  = blockIdx.z;
  const int i0 = blockIdx.y * 32;
  const int w0 = blockIdx.x * 47;
  const int j0 = w0 * 64;
  if (j0 + 3008 <= i0) return;   // whole block strictly below diagonal
  const int nj = min(3008, PRE_TOPN - j0);
  const int tid = threadIdx.x;
  const float4* S = (const float4*)(sbox + (size_t)b * PRE_TOPN * 4);
  for (int e = tid; e < nj; e += 256) jb[e] = S[j0 + e];
  if (tid < 32 && i0 + tid < PRE_TOPN) ib[tid] = S[i0 + tid];
  __syncthreads();
  for (int idx = tid; idx < 32 * 47; idx += 256) {
    const int il = idx / 47, wl = idx - il * 47;
    const int i = i0 + il;
    if (i >= PRE_TOPN) continue;
    if (((w0 + wl) << 6) + 63 < i) continue;   // word entirely below i: never consulted
    const float4 p = ib[il];
    const float parea = (p.z - p.x + 1.f) * (p.w - p.y + 1.f);
    unsigned long long m = 0;
    const int jb0 = wl * 64;
    #pragma unroll 8
    for (int q = 0; q < 64; ++q) {
      const int j = jb0 + q;
      const float4 qb = jb[j];
      float xx1 = fmaxf(p.x, qb.x), yy1 = fmaxf(p.y, qb.y);
      float xx2 = fminf(p.z, qb.z), yy2 = fminf(p.w, qb.w);
      float inter = fmaxf(xx2 - xx1 + 1.f, 0.f) * fmaxf(yy2 - yy1 + 1.f, 0.f);
      float area = (qb.z - qb.x + 1.f) * (qb.w - qb.y + 1.f);
      float iou = inter / (parea + area - inter);
      if (iou > 0.7f && j < nj) m |= (1ull << q);
    }
    mask[((size_t)b * PRE_TOPN + i) * MROW + w0 + wl] = m;
  }
}

// ---------------- wave-synchronous greedy pick ----------------
__device__ inline unsigned long long shfl_u64(unsigned long long v, int src) {
  int lo = __shfl((int)(unsigned)v, src, 64);
  int hi = __shfl((int)(unsigned)(v >> 32), src, 64);
  return ((unsigned long long)(unsigned)hi << 32) | (unsigned)lo;
}

__global__ __launch_bounds__(64) void nms_pick_k(const float* __restrict__ sbox,
                                                 const unsigned long long* __restrict__ mask,
                                                 float* __restrict__ out) {
  const int b = blockIdx.x;
  const int lane = threadIdx.x;
  unsigned long long va = ~0ull;
  unsigned long long vb = (lane < 29) ? ~0ull : (lane == 29 ? ((1ull << 48) - 1ull) : 0ull);
  const float* Bb = sbox + (size_t)b * PRE_TOPN * 4;
  float* O = out + (size_t)b * POST_TOPN * 5;
  int done = POST_TOPN;
  for (int it = 0; it < POST_TOPN; ++it) {
    unsigned long long ba = __ballot(va != 0ull);
    unsigned long long bb = __ballot(vb != 0ull);
    int w; unsigned long long word;
    if (ba) {
      w = __ffsll((long long)ba) - 1;
      word = shfl_u64(va, w);
    } else if (bb) {
      w = __ffsll((long long)bb) - 1;
      word = shfl_u64(vb, w);
      w += 64;
    } else { done = it; break; }
    const int i = (w << 6) + __ffsll((long long)word) - 1;
    const unsigned long long* row = mask + ((size_t)b * PRE_TOPN + i) * MROW;
    unsigned long long ra = row[lane];
    unsigned long long rb = (lane < 30) ? row[64 + lane] : 0ull;
    if (lane < 4) O[it * 5 + 1 + lane] = Bb[(size_t)i * 4 + lane];
    if (lane == 4) O[it * 5] = (float)b;
    va &= ~ra;
    vb &= ~rb;
  }
  for (int e = lane; e < (POST_TOPN - done) * 5; e += 64) {
    int r = done + e / 5; int c = e - (e / 5) * 5;
    O[r * 5 + c] = (c == 0) ? (float)b : 0.f;
  }
}

// ---------------- launch ----------------
extern "C" void kernel_launch(void* const* d_in, const int* in_sizes, int n_in,
                              void* d_out, int out_size, void* d_ws, size_t ws_size,
                              hipStream_t stream) {
  const float* base_feat = (const float*)d_in[0];
  const float* im_info   = (const float*)d_in[1];
  const float* W_conv    = (const float*)d_in[4];
  const float* b_conv    = (const float*)d_in[5];
  const float* W_cls     = (const float*)d_in[6];
  const float* b_cls     = (const float*)d_in[7];
  const float* W_bbox    = (const float*)d_in[8];
  const float* b_bbox    = (const float*)d_in[9];
  float* out = (float*)d_out;
  char* ws = (char*)d_ws;

  float*    Wt2   = (float*)(ws + OFF_WT2);
  float*    It    = (float*)(ws + OFF_IT);
  float*    conv  = (float*)(ws + OFF_CONV);
  unsigned long long* mask = (unsigned long long*)(ws + OFF_MASK);  // overlays It (dead after conv)
  float*    head  = (float*)(ws + OFF_HEAD);                        // overlays Wt2 (dead after conv)
  unsigned* skeys = (unsigned*)(ws + OFF_SKEY);
  float*    boxes = (float*)(ws + OFF_BOX);
  unsigned* hist  = (unsigned*)(ws + OFF_HIST);
  unsigned* misc  = (unsigned*)(ws + OFF_MISC);
  unsigned* ckey  = (unsigned*)(ws + OFF_CKEY);
  unsigned* cidx  = (unsigned*)(ws + OFF_CIDX);
  float*    sbox  = (float*)(ws + OFF_SBOX);

  hipMemsetAsync(ws + OFF_HIST, 0, 65536 + 256, stream);

  wtrans2_k<<<9216, 256, 0, stream>>>(W_conv, Wt2);
  cvtI_k<<<dim3(64, 8, 4), 256, 0, stream>>>(base_feat, It);
  conv_mfma_k<<<dim3(32, 4, 4), 256, 0, stream>>>(It, Wt2, b_conv, conv);
  head_mfma_k<<<dim3(32, 4), 256, 0, stream>>>(conv, W_cls, b_cls, W_bbox, b_bbox, head);
  decode_k<<<64, 256, 0, stream>>>(head, im_info, boxes, skeys, hist);
  select_k<<<4, 512, 0, stream>>>(skeys, hist, misc, ckey, cidx);
  rank_scatter_k<<<dim3(CAND_CAP / 256, 4), 256, 0, stream>>>(ckey, cidx, misc, boxes, sbox);
  iou_mask_k<<<dim3(2, 188, 4), 256, 0, stream>>>(sbox, mask);
  nms_pick_k<<<4, 64, 0, stream>>>(sbox, mask, out);
}